// Round 1
// baseline (5995.118 us; speedup 1.0000x reference)
//
#include <hip/hip_runtime.h>
#include <stdint.h>

typedef unsigned int u32;
typedef unsigned long long u64;

#define NN 8192
#define DD 512
#define CC 64            // NUM_CENTROIDS
#define RR 5             // NUM_KMEANS
#define KM_ITERS 20
#define TOPKK 16
#define CHUNK 1024       // sim row-chunk (bounds ws use to ~38 MB)

// JAX PRNG derivation: 1 = threefry_partitionable (default since JAX 0.4.36),
// 0 = original threefry split/bits. If bench fails with absmax ~1-2 (discrete
// mismatch only), flip this first.
#define JAX_PARTITIONABLE 1

// ---------------- Threefry-2x32, 20 rounds (matches jax/_src/prng.py) -------
__device__ __forceinline__ void tf2x32(u32 k0, u32 k1, u32 x0, u32 x1,
                                       u32& o0, u32& o1) {
  u32 ks2 = k0 ^ k1 ^ 0x1BD11BDAu;
  x0 += k0; x1 += k1;
#define TFR(r) { x0 += x1; x1 = (x1 << r) | (x1 >> (32 - r)); x1 ^= x0; }
  TFR(13) TFR(15) TFR(26) TFR(6)
  x0 += k1; x1 += ks2 + 1u;
  TFR(17) TFR(29) TFR(16) TFR(24)
  x0 += ks2; x1 += k0 + 2u;
  TFR(13) TFR(15) TFR(26) TFR(6)
  x0 += k0; x1 += k1 + 3u;
  TFR(17) TFR(29) TFR(16) TFR(24)
  x0 += k1; x1 += ks2 + 4u;
  TFR(13) TFR(15) TFR(26) TFR(6)
  x0 += ks2; x1 += k0 + 5u;
#undef TFR
  o0 = x0; o1 = x1;
}

// Generate the two rounds of shuffle sort-keys for all 5 runs.
// root key = (0, 1234) from jax.random.key(1234).
__global__ __launch_bounds__(256) void rng_kernel(u32* __restrict__ bits1,
                                                  u32* __restrict__ bits2) {
  int r = blockIdx.x;
  int i = blockIdx.y * 256 + threadIdx.x;   // 0..8191
#if JAX_PARTITIONABLE
  // keys[r] = enc(root,(0,r)); split: new=enc(k,(0,0)), sub=enc(k,(0,1));
  // bits32[i] = x1^x2 of enc(sub,(0,i))
  u32 rk0, rk1; tf2x32(0u, 1234u, 0u, (u32)r, rk0, rk1);
  u32 k10, k11, s10, s11, s20, s21;
  tf2x32(rk0, rk1, 0u, 0u, k10, k11);   // key after round-1 split
  tf2x32(rk0, rk1, 0u, 1u, s10, s11);   // subkey round 1
  tf2x32(k10, k11, 0u, 1u, s20, s21);   // subkey round 2
  u32 a, b;
  tf2x32(s10, s11, 0u, (u32)i, a, b);
  bits1[r * NN + i] = a ^ b;
  tf2x32(s20, s21, 0u, (u32)i, a, b);
  bits2[r * NN + i] = a ^ b;
#else
  // original: split(root,5): keys[r]=(enc(r,r+5).x1, enc(r,r+5).x2)
  // split(key): e0=enc(0,2), e1=enc(1,3): new=(e0.x1,e1.x1) sub=(e0.x2,e1.x2)
  // bits: pairs (i, i+4096): bits[i]=x1, bits[i+4096]=x2
  if (i >= NN / 2) return;
  u32 rk0, rk1; tf2x32(0u, 1234u, (u32)r, (u32)(r + RR), rk0, rk1);
  u32 e00, e01, e10, e11;
  tf2x32(rk0, rk1, 0u, 2u, e00, e01);
  tf2x32(rk0, rk1, 1u, 3u, e10, e11);
  u32 k10 = e00, k11 = e10, s10 = e01, s11 = e11;
  tf2x32(k10, k11, 0u, 2u, e00, e01);
  tf2x32(k10, k11, 1u, 3u, e10, e11);
  u32 s20 = e01, s21 = e11;
  u32 a, b;
  tf2x32(s10, s11, (u32)i, (u32)(i + NN / 2), a, b);
  bits1[r * NN + i] = a; bits1[r * NN + i + NN / 2] = b;
  tf2x32(s20, s21, (u32)i, (u32)(i + NN / 2), a, b);
  bits2[r * NN + i] = a; bits2[r * NN + i + NN / 2] = b;
#endif
}

// Stable sort round 1 via O(N^2) ranking: vout[rank(i)] = i.
// key = (bits, index) lexicographic => exact lax.sort_key_val stability.
__global__ __launch_bounds__(256) void rank1_kernel(const u32* __restrict__ bits,
                                                    int* __restrict__ vout) {
  __shared__ u32 sb[NN];
  int r = blockIdx.x;
  const u32* bb = bits + (size_t)r * NN;
  for (int t = threadIdx.x; t < NN; t += 256) sb[t] = bb[t];
  __syncthreads();
  int i = blockIdx.y * 256 + threadIdx.x;
  u32 mb = sb[i];
  int rank = 0;
  for (int j = 0; j < NN; ++j) {
    u32 v = sb[j];
    rank += (int)((v < mb) | ((v == mb) & (j < i)));
  }
  vout[(size_t)r * NN + rank] = i;
}

// Stable sort round 2; only final ranks < 64 matter (choice -> perm[:64]).
__global__ __launch_bounds__(256) void rank2_kernel(const u32* __restrict__ bits,
                                                    const int* __restrict__ v1,
                                                    int* __restrict__ sel) {
  __shared__ u32 sb[NN];
  int r = blockIdx.x;
  const u32* bb = bits + (size_t)r * NN;
  for (int t = threadIdx.x; t < NN; t += 256) sb[t] = bb[t];
  __syncthreads();
  int i = blockIdx.y * 256 + threadIdx.x;
  u32 mb = sb[i];
  int rank = 0;
  for (int j = 0; j < NN; ++j) {
    u32 v = sb[j];
    rank += (int)((v < mb) | ((v == mb) & (j < i)));
  }
  if (rank < CC) sel[r * CC + rank] = v1[(size_t)r * NN + i];
}

__global__ __launch_bounds__(256) void init_cent_kernel(const float* __restrict__ X,
                                                        const int* __restrict__ sel,
                                                        double* __restrict__ cent) {
  int r = blockIdx.x, c = blockIdx.y, t = threadIdx.x;
  int src = sel[r * CC + c];
  const float* xp = X + (size_t)src * DD;
  double* cp = cent + (size_t)(r * CC + c) * DD;
  cp[t] = (double)xp[t];
  cp[t + 256] = (double)xp[t + 256];
}

// labels[r][i] = argmin_c ( ||c||^2 - 2 x.c ), all in f64.
// grid (NN/64, RR), 256 threads, 64x64 tile, 4x4 micro (strided row/col maps).
__global__ __launch_bounds__(256) void assign_kernel(const float* __restrict__ X,
                                                     const double* __restrict__ cent,
                                                     int* __restrict__ labels) {
  __shared__ float  Xs[64][68];
  __shared__ double Cs[CC][66];
  __shared__ double cn[CC];
  int r = blockIdx.y;
  int rowBase = blockIdx.x * 64;
  int tid = threadIdx.x, tx = tid & 15, ty = tid >> 4;
  const double* cb = cent + (size_t)r * CC * DD;
  double acc[4][4] = {{0.0}};
  double cnacc = 0.0;
  for (int kc = 0; kc < DD; kc += 64) {
    // stage X tile (64 rows x 64 k, f32) with float4
    for (int l = 0; l < 4; ++l) {
      int idx4 = l * 256 + tid;
      int row = idx4 >> 4, k4 = (idx4 & 15) << 2;
      float4 v = *(const float4*)(X + (size_t)(rowBase + row) * DD + kc + k4);
      *(float4*)&Xs[row][k4] = v;
    }
    // stage centroid tile (64 c x 64 k, f64) with double2
    for (int l = 0; l < 8; ++l) {
      int idx2 = l * 256 + tid;
      int c = idx2 >> 5, k2 = (idx2 & 31) << 1;
      double2 v = *(const double2*)(cb + (size_t)c * DD + kc + k2);
      Cs[c][k2] = v.x; Cs[c][k2 + 1] = v.y;
    }
    __syncthreads();
    if (tid < CC) {            // fold ||c||^2 accumulation in
      double s = 0.0;
      for (int k = 0; k < 64; ++k) { double v = Cs[tid][k]; s += v * v; }
      cnacc += s;
    }
#pragma unroll 4
    for (int k = 0; k < 64; ++k) {
      double a0 = (double)Xs[ty][k],      a1 = (double)Xs[ty + 16][k];
      double a2 = (double)Xs[ty + 32][k], a3 = (double)Xs[ty + 48][k];
      double b0 = Cs[tx][k],      b1 = Cs[tx + 16][k];
      double b2 = Cs[tx + 32][k], b3 = Cs[tx + 48][k];
      acc[0][0] += a0 * b0; acc[0][1] += a0 * b1; acc[0][2] += a0 * b2; acc[0][3] += a0 * b3;
      acc[1][0] += a1 * b0; acc[1][1] += a1 * b1; acc[1][2] += a1 * b2; acc[1][3] += a1 * b3;
      acc[2][0] += a2 * b0; acc[2][1] += a2 * b1; acc[2][2] += a2 * b2; acc[2][3] += a2 * b3;
      acc[3][0] += a3 * b0; acc[3][1] += a3 * b1; acc[3][2] += a3 * b2; acc[3][3] += a3 * b3;
    }
    __syncthreads();
  }
  if (tid < CC) cn[tid] = cnacc;
  __syncthreads();
  double* dmat = &Cs[0][0];   // reuse as [64][66] distance matrix
#pragma unroll
  for (int i = 0; i < 4; ++i)
#pragma unroll
    for (int j = 0; j < 4; ++j)
      dmat[(size_t)(ty + 16 * i) * 66 + (tx + 16 * j)] =
          cn[tx + 16 * j] - 2.0 * acc[i][j];
  __syncthreads();
  if (tid < 64) {
    const double* dr = dmat + (size_t)tid * 66;
    double best = dr[0]; int bi = 0;
    for (int c = 1; c < CC; ++c) { double v = dr[c]; if (v < best) { best = v; bi = c; } }
    labels[(size_t)r * NN + rowBase + tid] = bi;   // strict < = first-min (jnp.argmin)
  }
}

// per-256-block histogram + stable rank-in-block (for counting sort of members)
__global__ __launch_bounds__(256) void hist_kernel(const int* __restrict__ labels,
                                                   int* __restrict__ bhist,
                                                   int* __restrict__ rib) {
  __shared__ int ls[256];
  __shared__ int h[CC];
  int r = blockIdx.x, blk = blockIdx.y, tid = threadIdx.x;
  int i = blk * 256 + tid;
  int lab = labels[(size_t)r * NN + i];
  ls[tid] = lab;
  if (tid < CC) h[tid] = 0;
  __syncthreads();
  atomicAdd(&h[lab], 1);
  int rk = 0;
  for (int j = 0; j < tid; ++j) rk += (ls[j] == lab);
  rib[(size_t)r * NN + i] = rk;
  __syncthreads();
  if (tid < CC) bhist[(size_t)(r * 32 + blk) * CC + tid] = h[tid];
}

__global__ void scan_kernel(const int* __restrict__ bhist, int* __restrict__ boff,
                            int* __restrict__ cstart, int* __restrict__ cnt) {
  int r = blockIdx.x, c = threadIdx.x;   // 64 threads
  int tot = 0;
  for (int b = 0; b < 32; ++b) {
    boff[(size_t)(r * 32 + b) * CC + c] = tot;
    tot += bhist[(size_t)(r * 32 + b) * CC + c];
  }
  cnt[r * CC + c] = tot;
  __shared__ int s[CC];
  s[c] = tot;
  __syncthreads();
  if (c == 0) { int run = 0; for (int q = 0; q < CC; ++q) { int t = s[q]; s[q] = run; run += t; } }
  __syncthreads();
  cstart[r * CC + c] = s[c];
}

__global__ __launch_bounds__(256) void fill_kernel(const int* __restrict__ labels,
                                                   const int* __restrict__ rib,
                                                   const int* __restrict__ boff,
                                                   const int* __restrict__ cstart,
                                                   int* __restrict__ member) {
  int r = blockIdx.x, blk = blockIdx.y, tid = threadIdx.x;
  int i = blk * 256 + tid;
  int lab = labels[(size_t)r * NN + i];
  int pos = cstart[r * CC + lab] + boff[(size_t)(r * 32 + blk) * CC + lab] +
            rib[(size_t)r * NN + i];
  member[(size_t)r * NN + pos] = i;   // sorted by (cluster, index ascending)
}

// centroid update: f64 sums over members (order-free in f64), / count, or keep old.
__global__ __launch_bounds__(256) void update_kernel(const float* __restrict__ X,
                                                     const int* __restrict__ member,
                                                     const int* __restrict__ cstart,
                                                     const int* __restrict__ cnt,
                                                     const double* __restrict__ centOld,
                                                     double* __restrict__ centNew) {
  int r = blockIdx.x, c = blockIdx.y, tid = threadIdx.x;
  int n = cnt[r * CC + c];
  int st = cstart[r * CC + c];
  const int* mem = member + (size_t)r * NN + st;
  double s0a = 0, s1a = 0, s2a = 0, s3a = 0, s0b = 0, s1b = 0, s2b = 0, s3b = 0;
  int m = 0;
  for (; m + 4 <= n; m += 4) {   // 4-way ILP to hide load latency
    const float* p0 = X + (size_t)mem[m + 0] * DD;
    const float* p1 = X + (size_t)mem[m + 1] * DD;
    const float* p2 = X + (size_t)mem[m + 2] * DD;
    const float* p3 = X + (size_t)mem[m + 3] * DD;
    s0a += (double)p0[tid]; s0b += (double)p0[tid + 256];
    s1a += (double)p1[tid]; s1b += (double)p1[tid + 256];
    s2a += (double)p2[tid]; s2b += (double)p2[tid + 256];
    s3a += (double)p3[tid]; s3b += (double)p3[tid + 256];
  }
  for (; m < n; ++m) {
    const float* p = X + (size_t)mem[m] * DD;
    s0a += (double)p[tid]; s0b += (double)p[tid + 256];
  }
  double sa = (s0a + s1a) + (s2a + s3a);
  double sb = (s0b + s1b) + (s2b + s3b);
  size_t o = (size_t)(r * CC + c) * DD;
  double va, vb;
  if (n > 0) { double inv = (double)n; va = sa / inv; vb = sb / inv; }
  else       { va = centOld[o + tid];  vb = centOld[o + tid + 256]; }
  centNew[o + tid] = va;
  centNew[o + tid + 256] = vb;
}

// sim chunk GEMM: f32 products, per-64-k f32 accumulate, f64 chunk combine
// (keeps |err| ~1e-6 vs exact so top-k ranks match a f64 reference).
__global__ __launch_bounds__(256) void gemm_kernel(const float* __restrict__ S,
                                                   const float* __restrict__ T,
                                                   float* __restrict__ sim,
                                                   int rowChunk) {
  __shared__ float As[64][68];
  __shared__ float Bs[64][68];
  int tid = threadIdx.x, tx = tid & 15, ty = tid >> 4;
  int rowBase = rowChunk + blockIdx.y * 64;
  int colBase = blockIdx.x * 64;
  float  a32[4][4] = {{0.f}};
  double a64[4][4] = {{0.0}};
  for (int kc = 0; kc < DD; kc += 64) {
    for (int l = 0; l < 4; ++l) {
      int idx4 = l * 256 + tid;
      int row = idx4 >> 4, k4 = (idx4 & 15) << 2;
      float4 v = *(const float4*)(S + (size_t)(rowBase + row) * DD + kc + k4);
      *(float4*)&As[row][k4] = v;
      float4 w = *(const float4*)(T + (size_t)(colBase + row) * DD + kc + k4);
      *(float4*)&Bs[row][k4] = w;
    }
    __syncthreads();
#pragma unroll 8
    for (int k = 0; k < 64; ++k) {
      float a0 = As[ty][k],      a1 = As[ty + 16][k];
      float a2 = As[ty + 32][k], a3 = As[ty + 48][k];
      float b0 = Bs[tx][k],      b1 = Bs[tx + 16][k];
      float b2 = Bs[tx + 32][k], b3 = Bs[tx + 48][k];
      a32[0][0] += a0 * b0; a32[0][1] += a0 * b1; a32[0][2] += a0 * b2; a32[0][3] += a0 * b3;
      a32[1][0] += a1 * b0; a32[1][1] += a1 * b1; a32[1][2] += a1 * b2; a32[1][3] += a1 * b3;
      a32[2][0] += a2 * b0; a32[2][1] += a2 * b1; a32[2][2] += a2 * b2; a32[2][3] += a2 * b3;
      a32[3][0] += a3 * b0; a32[3][1] += a3 * b1; a32[3][2] += a3 * b2; a32[3][3] += a3 * b3;
    }
    __syncthreads();
#pragma unroll
    for (int i = 0; i < 4; ++i)
#pragma unroll
      for (int j = 0; j < 4; ++j) { a64[i][j] += (double)a32[i][j]; a32[i][j] = 0.f; }
  }
#pragma unroll
  for (int i = 0; i < 4; ++i)
#pragma unroll
    for (int j = 0; j < 4; ++j) {
      int lrow = blockIdx.y * 64 + ty + 16 * i;
      int gcol = colBase + tx + 16 * j;
      int grow = rowChunk + lrow;
      float v = (float)a64[i][j];
      if (grow == gcol) v += 10.0f;
      sim[(size_t)lrow * NN + gcol] = v;
    }
}

// per-row top-16 with jax.lax.top_k tie semantics (equal value -> lower index).
__global__ __launch_bounds__(256) void topk_kernel(const float* __restrict__ sim,
                                                   int* __restrict__ iknn,
                                                   int rowChunk) {
  __shared__ float rowv[NN];      // 32 KB
  __shared__ u64 red[4];
  int blk = blockIdx.x;           // local chunk row
  int tid = threadIdx.x;
  const float* rp = sim + (size_t)blk * NN;
  for (int t = tid; t < NN; t += 256) rowv[t] = rp[t];
  __syncthreads();
  int grow = rowChunk + blk;
  for (int k = 0; k < TOPKK; ++k) {
    u64 best = 0;
    for (int t = tid; t < NN; t += 256) {
      float v = rowv[t];
      u32 u = __float_as_uint(v);
      u = (u & 0x80000000u) ? ~u : (u | 0x80000000u);   // order-preserving map
      u64 key = ((u64)u << 32) | (u32)(NN - 1 - t);     // tie -> smaller index wins
      best = key > best ? key : best;
    }
    for (int off = 32; off > 0; off >>= 1) {
      u32 lo = (u32)best, hi = (u32)(best >> 32);
      lo = __shfl_down(lo, off, 64); hi = __shfl_down(hi, off, 64);
      u64 o = ((u64)hi << 32) | lo;
      best = o > best ? o : best;
    }
    if ((tid & 63) == 0) red[tid >> 6] = best;
    __syncthreads();
    if (tid == 0) {
      u64 b = red[0];
      for (int w = 1; w < 4; ++w) b = red[w] > b ? red[w] : b;
      int t = (NN - 1) - (int)(b & 0xFFFFFFFFu);
      iknn[(size_t)grow * TOPKK + k] = t;
      rowv[t] = -__builtin_inff();
    }
    __syncthreads();
  }
}

__global__ __launch_bounds__(256) void zero_kernel(float4* __restrict__ out) {
  size_t i = (size_t)blockIdx.x * 256 + threadIdx.x;
  out[i] = make_float4(0.f, 0.f, 0.f, 0.f);
}

__global__ __launch_bounds__(256) void scatter_kernel(const float* __restrict__ adj,
                                                      const int* __restrict__ iknn,
                                                      const int* __restrict__ labels,
                                                      float* __restrict__ out) {
  int idx = blockIdx.x * 256 + threadIdx.x;   // NN*TOPKK work items
  int i = idx >> 4;
  int col = iknn[idx];
  int m = 0;
#pragma unroll
  for (int r = 0; r < RR; ++r)
    m |= (labels[(size_t)r * NN + i] == labels[(size_t)r * NN + col]);
  size_t o = (size_t)i * NN + col;
  out[o] = adj[o] + (float)m;   // locality (=adj at knn) + glob_pat (=mask)
}

extern "C" void kernel_launch(void* const* d_in, const int* in_sizes, int n_in,
                              void* d_out, int out_size, void* d_ws, size_t ws_size,
                              hipStream_t stream) {
  (void)in_sizes; (void)n_in; (void)out_size; (void)ws_size;
  const float* adj     = (const float*)d_in[0];
  const float* student = (const float*)d_in[1];
  const float* teacher = (const float*)d_in[2];
  float* out = (float*)d_out;

  char* p = (char*)d_ws;
  auto alloc = [&](size_t bytes) -> void* {
    void* q = (void*)p; p += (bytes + 255) & ~(size_t)255; return q;
  };
  double* centA  = (double*)alloc((size_t)RR * CC * DD * 8);
  double* centB  = (double*)alloc((size_t)RR * CC * DD * 8);
  u32*    bits1  = (u32*)   alloc((size_t)RR * NN * 4);
  u32*    bits2  = (u32*)   alloc((size_t)RR * NN * 4);
  int*    v1     = (int*)   alloc((size_t)RR * NN * 4);
  int*    sel    = (int*)   alloc((size_t)RR * CC * 4);
  int*    labels = (int*)   alloc((size_t)RR * NN * 4);
  int*    bhist  = (int*)   alloc((size_t)RR * 32 * CC * 4);
  int*    boff   = (int*)   alloc((size_t)RR * 32 * CC * 4);
  int*    cstart = (int*)   alloc((size_t)RR * CC * 4);
  int*    cnt    = (int*)   alloc((size_t)RR * CC * 4);
  int*    rib    = (int*)   alloc((size_t)RR * NN * 4);
  int*    member = (int*)   alloc((size_t)RR * NN * 4);
  int*    iknn   = (int*)   alloc((size_t)NN * TOPKK * 4);
  float*  simc   = (float*) alloc((size_t)CHUNK * NN * 4);

  // --- k-means init: JAX threefry choice(key, 8192, (64,), replace=False) ---
  rng_kernel<<<dim3(RR, 32), 256, 0, stream>>>(bits1, bits2);
  rank1_kernel<<<dim3(RR, 32), 256, 0, stream>>>(bits1, v1);
  rank2_kernel<<<dim3(RR, 32), 256, 0, stream>>>(bits2, v1, sel);
  init_cent_kernel<<<dim3(RR, CC), 256, 0, stream>>>(teacher, sel, centA);

  // --- 20 Lloyd iterations, all-f64 ---
  double* cur = centA; double* nxt = centB;
  for (int it = 0; it < KM_ITERS; ++it) {
    assign_kernel<<<dim3(NN / 64, RR), 256, 0, stream>>>(teacher, cur, labels);
    hist_kernel<<<dim3(RR, 32), 256, 0, stream>>>(labels, bhist, rib);
    scan_kernel<<<RR, CC, 0, stream>>>(bhist, boff, cstart, cnt);
    fill_kernel<<<dim3(RR, 32), 256, 0, stream>>>(labels, rib, boff, cstart, member);
    update_kernel<<<dim3(RR, CC), 256, 0, stream>>>(teacher, member, cstart, cnt, cur, nxt);
    double* t = cur; cur = nxt; nxt = t;
  }
  assign_kernel<<<dim3(NN / 64, RR), 256, 0, stream>>>(teacher, cur, labels);

  // --- sim = student @ teacher.T (+10 I) in row chunks, then per-row top-16 ---
  for (int ch = 0; ch < NN / CHUNK; ++ch) {
    gemm_kernel<<<dim3(NN / 64, CHUNK / 64), 256, 0, stream>>>(student, teacher, simc,
                                                               ch * CHUNK);
    topk_kernel<<<CHUNK, 256, 0, stream>>>(simc, iknn, ch * CHUNK);
  }

  // --- pos = 0 everywhere; pos[i, knn] = adj + mask ---
  zero_kernel<<<(unsigned)((size_t)NN * NN / 4 / 256), 256, 0, stream>>>((float4*)out);
  scatter_kernel<<<NN * TOPKK / 256, 256, 0, stream>>>(adj, iknn, labels, out);
}

// Round 2
// 5892.116 us; speedup vs baseline: 1.0175x; 1.0175x over previous
//
#include <hip/hip_runtime.h>
#include <stdint.h>

typedef unsigned int u32;
typedef unsigned long long u64;

#define NN 8192
#define DD 512
#define CC 64            // NUM_CENTROIDS
#define RR 5             // NUM_KMEANS
#define KM_ITERS 20
#define TOPKK 16
#define CHUNK 1024       // sim row-chunk (bounds ws use to ~42 MB)
#define FIXCAP (RR * NN) // flag capacity per iteration
#define GAP_TH 0.05f     // f32 gap below which we re-decide in f64

// JAX PRNG derivation: 1 = threefry_partitionable (verified correct in R1).
#define JAX_PARTITIONABLE 1

// ---------------- Threefry-2x32, 20 rounds (matches jax/_src/prng.py) -------
__device__ __forceinline__ void tf2x32(u32 k0, u32 k1, u32 x0, u32 x1,
                                       u32& o0, u32& o1) {
  u32 ks2 = k0 ^ k1 ^ 0x1BD11BDAu;
  x0 += k0; x1 += k1;
#define TFR(r) { x0 += x1; x1 = (x1 << r) | (x1 >> (32 - r)); x1 ^= x0; }
  TFR(13) TFR(15) TFR(26) TFR(6)
  x0 += k1; x1 += ks2 + 1u;
  TFR(17) TFR(29) TFR(16) TFR(24)
  x0 += ks2; x1 += k0 + 2u;
  TFR(13) TFR(15) TFR(26) TFR(6)
  x0 += k0; x1 += k1 + 3u;
  TFR(17) TFR(29) TFR(16) TFR(24)
  x0 += k1; x1 += ks2 + 4u;
  TFR(13) TFR(15) TFR(26) TFR(6)
  x0 += ks2; x1 += k0 + 5u;
#undef TFR
  o0 = x0; o1 = x1;
}

__global__ __launch_bounds__(256) void rng_kernel(u32* __restrict__ bits1,
                                                  u32* __restrict__ bits2) {
  int r = blockIdx.x;
  int i = blockIdx.y * 256 + threadIdx.x;
#if JAX_PARTITIONABLE
  u32 rk0, rk1; tf2x32(0u, 1234u, 0u, (u32)r, rk0, rk1);
  u32 k10, k11, s10, s11, s20, s21;
  tf2x32(rk0, rk1, 0u, 0u, k10, k11);
  tf2x32(rk0, rk1, 0u, 1u, s10, s11);
  tf2x32(k10, k11, 0u, 1u, s20, s21);
  u32 a, b;
  tf2x32(s10, s11, 0u, (u32)i, a, b);
  bits1[r * NN + i] = a ^ b;
  tf2x32(s20, s21, 0u, (u32)i, a, b);
  bits2[r * NN + i] = a ^ b;
#else
  if (i >= NN / 2) return;
  u32 rk0, rk1; tf2x32(0u, 1234u, (u32)r, (u32)(r + RR), rk0, rk1);
  u32 e00, e01, e10, e11;
  tf2x32(rk0, rk1, 0u, 2u, e00, e01);
  tf2x32(rk0, rk1, 1u, 3u, e10, e11);
  u32 k10 = e00, k11 = e10, s10 = e01, s11 = e11;
  tf2x32(k10, k11, 0u, 2u, e00, e01);
  tf2x32(k10, k11, 1u, 3u, e10, e11);
  u32 s20 = e01, s21 = e11;
  u32 a, b;
  tf2x32(s10, s11, (u32)i, (u32)(i + NN / 2), a, b);
  bits1[r * NN + i] = a; bits1[r * NN + i + NN / 2] = b;
  tf2x32(s20, s21, (u32)i, (u32)(i + NN / 2), a, b);
  bits2[r * NN + i] = a; bits2[r * NN + i + NN / 2] = b;
#endif
}

// Partial stable-rank: key = (bits<<13)|j; count keys < mine in a 2048-j chunk.
// grid (RR, 32, 4) = 640 blocks.
__global__ __launch_bounds__(256) void rankpart_kernel(const u32* __restrict__ bits,
                                                       u32* __restrict__ prank) {
  __shared__ u64 sk[2048];
  int r = blockIdx.x, zc = blockIdx.z;
  const u32* bb = bits + (size_t)r * NN;
  int jbase = zc * 2048;
  for (int t = threadIdx.x; t < 2048; t += 256)
    sk[t] = ((u64)bb[jbase + t] << 13) | (u32)(jbase + t);
  __syncthreads();
  int i = blockIdx.y * 256 + threadIdx.x;
  u64 ki = ((u64)bb[i] << 13) | (u32)i;
  int cnt = 0;
#pragma unroll 8
  for (int j = 0; j < 2048; ++j) cnt += (int)(sk[j] < ki);
  prank[(size_t)(r * 4 + zc) * NN + i] = cnt;
}

__global__ __launch_bounds__(256) void scat1_kernel(const u32* __restrict__ prank,
                                                    int* __restrict__ vout) {
  int r = blockIdx.x;
  int i = blockIdx.y * 256 + threadIdx.x;
  int rank = prank[(size_t)(r * 4 + 0) * NN + i] + prank[(size_t)(r * 4 + 1) * NN + i] +
             prank[(size_t)(r * 4 + 2) * NN + i] + prank[(size_t)(r * 4 + 3) * NN + i];
  vout[(size_t)r * NN + rank] = i;
}

__global__ __launch_bounds__(256) void scat2_kernel(const u32* __restrict__ prank,
                                                    const int* __restrict__ v1,
                                                    int* __restrict__ sel) {
  int r = blockIdx.x;
  int i = blockIdx.y * 256 + threadIdx.x;
  int rank = prank[(size_t)(r * 4 + 0) * NN + i] + prank[(size_t)(r * 4 + 1) * NN + i] +
             prank[(size_t)(r * 4 + 2) * NN + i] + prank[(size_t)(r * 4 + 3) * NN + i];
  if (rank < CC) sel[r * CC + rank] = v1[(size_t)r * NN + i];
}

__device__ __forceinline__ double block_reduce_d(double s, double* red4) {
  int tid = threadIdx.x;
  for (int off = 32; off > 0; off >>= 1) s += __shfl_down(s, off, 64);
  if ((tid & 63) == 0) red4[tid >> 6] = s;
  __syncthreads();
  return red4[0] + red4[1] + red4[2] + red4[3];
}

__global__ __launch_bounds__(256) void init_cent_kernel(const float* __restrict__ X,
                                                        const int* __restrict__ sel,
                                                        double* __restrict__ centD,
                                                        float* __restrict__ centF,
                                                        double* __restrict__ cnD,
                                                        float* __restrict__ cnF) {
  __shared__ double red4[4];
  int r = blockIdx.x, c = blockIdx.y, t = threadIdx.x;
  int src = sel[r * CC + c];
  const float* xp = X + (size_t)src * DD;
  size_t o = (size_t)(r * CC + c) * DD;
  double va = (double)xp[t], vb = (double)xp[t + 256];
  centD[o + t] = va; centD[o + t + 256] = vb;
  centF[o + t] = (float)va; centF[o + t + 256] = (float)vb;
  double tot = block_reduce_d(va * va + vb * vb, red4);
  if (t == 0) { cnD[r * CC + c] = tot; cnF[r * CC + c] = (float)tot; }
}

// f32 assign with best/second gap tracking; marginal points flagged for f64 fixup.
__global__ __launch_bounds__(256) void assign_kernel(const float* __restrict__ X,
                                                     const float* __restrict__ centF,
                                                     const float* __restrict__ cnF,
                                                     int* __restrict__ labels,
                                                     u32* __restrict__ flags,
                                                     u32* __restrict__ counter) {
  __shared__ float Xs[64][68];
  __shared__ float Cs[64][68];
  int r = blockIdx.y;
  int rowBase = blockIdx.x * 64;
  int tid = threadIdx.x, tx = tid & 15, ty = tid >> 4;
  const float* cb = centF + (size_t)r * CC * DD;
  float acc[4][4] = {{0.f}};
  for (int kc = 0; kc < DD; kc += 64) {
    for (int l = 0; l < 4; ++l) {
      int idx4 = l * 256 + tid;
      int row = idx4 >> 4, k4 = (idx4 & 15) << 2;
      *(float4*)&Xs[row][k4] = *(const float4*)(X + (size_t)(rowBase + row) * DD + kc + k4);
      *(float4*)&Cs[row][k4] = *(const float4*)(cb + (size_t)row * DD + kc + k4);
    }
    __syncthreads();
    for (int k = 0; k < 64; k += 4) {
      float4 av[4], bv[4];
      av[0] = *(float4*)&Xs[ty][k];      av[1] = *(float4*)&Xs[ty + 16][k];
      av[2] = *(float4*)&Xs[ty + 32][k]; av[3] = *(float4*)&Xs[ty + 48][k];
      bv[0] = *(float4*)&Cs[tx][k];      bv[1] = *(float4*)&Cs[tx + 16][k];
      bv[2] = *(float4*)&Cs[tx + 32][k]; bv[3] = *(float4*)&Cs[tx + 48][k];
#pragma unroll
      for (int i = 0; i < 4; ++i)
#pragma unroll
        for (int j = 0; j < 4; ++j)
          acc[i][j] += av[i].x * bv[j].x + av[i].y * bv[j].y +
                       av[i].z * bv[j].z + av[i].w * bv[j].w;
    }
    __syncthreads();
  }
  float* dmat = &Cs[0][0];   // reuse Cs as [64][68] distance matrix
#pragma unroll
  for (int i = 0; i < 4; ++i)
#pragma unroll
    for (int j = 0; j < 4; ++j)
      dmat[(size_t)(ty + 16 * i) * 68 + (tx + 16 * j)] =
          cnF[r * CC + tx + 16 * j] - 2.0f * acc[i][j];
  __syncthreads();
  if (tid < 64) {
    const float* dr = dmat + (size_t)tid * 68;
    float best = dr[0], second = 3.4e38f; int bi = 0;
    for (int c = 1; c < CC; ++c) {
      float v = dr[c];
      if (v < best) { second = best; best = v; bi = c; }
      else if (v < second) second = v;
    }
    labels[(size_t)r * NN + rowBase + tid] = bi;
    if (second - best < GAP_TH) {
      u32 idx = atomicAdd(counter, 1u);
      flags[idx] = (u32)(r * NN + rowBase + tid);
    }
  }
}

// Exact f64 re-decision for flagged (marginal) points. Fixed 64-block grid.
__global__ __launch_bounds__(256) void fixup_kernel(const float* __restrict__ X,
                                                    const double* __restrict__ centD,
                                                    const double* __restrict__ cnD,
                                                    const u32* __restrict__ flags,
                                                    const u32* __restrict__ counter,
                                                    int* __restrict__ labels) {
  __shared__ double darr[CC];
  int n = (int)*counter;
  int tid = threadIdx.x, c = tid >> 2, sub = tid & 3;
  for (int f = blockIdx.x; f < n; f += gridDim.x) {
    u32 pk = flags[f];
    int r = pk >> 13, i = pk & (NN - 1);
    const float* x = X + (size_t)i * DD + sub * 128;
    const double* cp = centD + (size_t)(r * CC + c) * DD + sub * 128;
    double s = 0.0;
    for (int k = 0; k < 128; ++k) s += (double)x[k] * cp[k];
    s += __shfl_down(s, 2, 64);
    s += __shfl_down(s, 1, 64);
    if (sub == 0) darr[c] = cnD[r * CC + c] - 2.0 * s;
    __syncthreads();
    if (tid == 0) {
      double best = darr[0]; int bi = 0;
      for (int cc = 1; cc < CC; ++cc) { double v = darr[cc]; if (v < best) { best = v; bi = cc; } }
      labels[(size_t)r * NN + i] = bi;
    }
    __syncthreads();
  }
}

__global__ __launch_bounds__(256) void hist_kernel(const int* __restrict__ labels,
                                                   int* __restrict__ bhist,
                                                   int* __restrict__ rib) {
  __shared__ int ls[256];
  __shared__ int h[CC];
  int r = blockIdx.x, blk = blockIdx.y, tid = threadIdx.x;
  int i = blk * 256 + tid;
  int lab = labels[(size_t)r * NN + i];
  ls[tid] = lab;
  if (tid < CC) h[tid] = 0;
  __syncthreads();
  atomicAdd(&h[lab], 1);
  int rk = 0;
  for (int j = 0; j < tid; ++j) rk += (ls[j] == lab);
  rib[(size_t)r * NN + i] = rk;
  __syncthreads();
  if (tid < CC) bhist[(size_t)(r * 32 + blk) * CC + tid] = h[tid];
}

__global__ void scan_kernel(const int* __restrict__ bhist, int* __restrict__ boff,
                            int* __restrict__ cstart, int* __restrict__ cnt) {
  int r = blockIdx.x, c = threadIdx.x;
  int tot = 0;
  for (int b = 0; b < 32; ++b) {
    boff[(size_t)(r * 32 + b) * CC + c] = tot;
    tot += bhist[(size_t)(r * 32 + b) * CC + c];
  }
  cnt[r * CC + c] = tot;
  __shared__ int s[CC];
  s[c] = tot;
  __syncthreads();
  if (c == 0) { int run = 0; for (int q = 0; q < CC; ++q) { int t = s[q]; s[q] = run; run += t; } }
  __syncthreads();
  cstart[r * CC + c] = s[c];
}

__global__ __launch_bounds__(256) void fill_kernel(const int* __restrict__ labels,
                                                   const int* __restrict__ rib,
                                                   const int* __restrict__ boff,
                                                   const int* __restrict__ cstart,
                                                   int* __restrict__ member) {
  int r = blockIdx.x, blk = blockIdx.y, tid = threadIdx.x;
  int i = blk * 256 + tid;
  int lab = labels[(size_t)r * NN + i];
  int pos = cstart[r * CC + lab] + boff[(size_t)(r * 32 + blk) * CC + lab] +
            rib[(size_t)r * NN + i];
  member[(size_t)r * NN + pos] = i;
}

__global__ __launch_bounds__(256) void update_kernel(const float* __restrict__ X,
                                                     const int* __restrict__ member,
                                                     const int* __restrict__ cstart,
                                                     const int* __restrict__ cnt,
                                                     const double* __restrict__ centOld,
                                                     double* __restrict__ centNew,
                                                     float* __restrict__ centF,
                                                     double* __restrict__ cnD,
                                                     float* __restrict__ cnF) {
  __shared__ double red4[4];
  int r = blockIdx.x, c = blockIdx.y, tid = threadIdx.x;
  int n = cnt[r * CC + c];
  int st = cstart[r * CC + c];
  const int* mem = member + (size_t)r * NN + st;
  double s0a = 0, s1a = 0, s2a = 0, s3a = 0, s0b = 0, s1b = 0, s2b = 0, s3b = 0;
  int m = 0;
  for (; m + 4 <= n; m += 4) {
    const float* p0 = X + (size_t)mem[m + 0] * DD;
    const float* p1 = X + (size_t)mem[m + 1] * DD;
    const float* p2 = X + (size_t)mem[m + 2] * DD;
    const float* p3 = X + (size_t)mem[m + 3] * DD;
    s0a += (double)p0[tid]; s0b += (double)p0[tid + 256];
    s1a += (double)p1[tid]; s1b += (double)p1[tid + 256];
    s2a += (double)p2[tid]; s2b += (double)p2[tid + 256];
    s3a += (double)p3[tid]; s3b += (double)p3[tid + 256];
  }
  for (; m < n; ++m) {
    const float* p = X + (size_t)mem[m] * DD;
    s0a += (double)p[tid]; s0b += (double)p[tid + 256];
  }
  double sa = (s0a + s1a) + (s2a + s3a);
  double sb = (s0b + s1b) + (s2b + s3b);
  size_t o = (size_t)(r * CC + c) * DD;
  double va, vb;
  if (n > 0) { double inv = (double)n; va = sa / inv; vb = sb / inv; }
  else       { va = centOld[o + tid];  vb = centOld[o + tid + 256]; }
  centNew[o + tid] = va;
  centNew[o + tid + 256] = vb;
  centF[o + tid] = (float)va;
  centF[o + tid + 256] = (float)vb;
  double tot = block_reduce_d(va * va + vb * vb, red4);
  if (tid == 0) { cnD[r * CC + c] = tot; cnF[r * CC + c] = (float)tot; }
}

// sim chunk GEMM: f32 products, f32 per-64-k chunk accumulate (bitwise-identical
// add order to R1), f64 chunk combine. float4-k micro-kernel.
__global__ __launch_bounds__(256) void gemm_kernel(const float* __restrict__ S,
                                                   const float* __restrict__ T,
                                                   float* __restrict__ sim,
                                                   int rowChunk) {
  __shared__ float As[64][68];
  __shared__ float Bs[64][68];
  int tid = threadIdx.x, tx = tid & 15, ty = tid >> 4;
  int rowBase = rowChunk + blockIdx.y * 64;
  int colBase = blockIdx.x * 64;
  float  a32[4][4] = {{0.f}};
  double a64[4][4] = {{0.0}};
  for (int kc = 0; kc < DD; kc += 64) {
    for (int l = 0; l < 4; ++l) {
      int idx4 = l * 256 + tid;
      int row = idx4 >> 4, k4 = (idx4 & 15) << 2;
      *(float4*)&As[row][k4] = *(const float4*)(S + (size_t)(rowBase + row) * DD + kc + k4);
      *(float4*)&Bs[row][k4] = *(const float4*)(T + (size_t)(colBase + row) * DD + kc + k4);
    }
    __syncthreads();
    for (int k = 0; k < 64; k += 4) {
      float4 av[4], bv[4];
      av[0] = *(float4*)&As[ty][k];      av[1] = *(float4*)&As[ty + 16][k];
      av[2] = *(float4*)&As[ty + 32][k]; av[3] = *(float4*)&As[ty + 48][k];
      bv[0] = *(float4*)&Bs[tx][k];      bv[1] = *(float4*)&Bs[tx + 16][k];
      bv[2] = *(float4*)&Bs[tx + 32][k]; bv[3] = *(float4*)&Bs[tx + 48][k];
#pragma unroll
      for (int i = 0; i < 4; ++i)
#pragma unroll
        for (int j = 0; j < 4; ++j)
          a32[i][j] += av[i].x * bv[j].x + av[i].y * bv[j].y +
                       av[i].z * bv[j].z + av[i].w * bv[j].w;
    }
    __syncthreads();
#pragma unroll
    for (int i = 0; i < 4; ++i)
#pragma unroll
      for (int j = 0; j < 4; ++j) { a64[i][j] += (double)a32[i][j]; a32[i][j] = 0.f; }
  }
#pragma unroll
  for (int i = 0; i < 4; ++i)
#pragma unroll
    for (int j = 0; j < 4; ++j) {
      int lrow = blockIdx.y * 64 + ty + 16 * i;
      int gcol = colBase + tx + 16 * j;
      int grow = rowChunk + lrow;
      float v = (float)a64[i][j];
      if (grow == gcol) v += 10.0f;
      sim[(size_t)lrow * NN + gcol] = v;
    }
}

__global__ __launch_bounds__(256) void topk_kernel(const float* __restrict__ sim,
                                                   int* __restrict__ iknn,
                                                   int rowChunk) {
  __shared__ float rowv[NN];
  __shared__ u64 red[4];
  int blk = blockIdx.x;
  int tid = threadIdx.x;
  const float* rp = sim + (size_t)blk * NN;
  for (int t = tid; t < NN; t += 256) rowv[t] = rp[t];
  __syncthreads();
  int grow = rowChunk + blk;
  for (int k = 0; k < TOPKK; ++k) {
    u64 best = 0;
    for (int t = tid; t < NN; t += 256) {
      float v = rowv[t];
      u32 u = __float_as_uint(v);
      u = (u & 0x80000000u) ? ~u : (u | 0x80000000u);
      u64 key = ((u64)u << 32) | (u32)(NN - 1 - t);
      best = key > best ? key : best;
    }
    for (int off = 32; off > 0; off >>= 1) {
      u32 lo = (u32)best, hi = (u32)(best >> 32);
      lo = __shfl_down(lo, off, 64); hi = __shfl_down(hi, off, 64);
      u64 o = ((u64)hi << 32) | lo;
      best = o > best ? o : best;
    }
    if ((tid & 63) == 0) red[tid >> 6] = best;
    __syncthreads();
    if (tid == 0) {
      u64 b = red[0];
      for (int w = 1; w < 4; ++w) b = red[w] > b ? red[w] : b;
      int t = (NN - 1) - (int)(b & 0xFFFFFFFFu);
      iknn[(size_t)grow * TOPKK + k] = t;
      rowv[t] = -__builtin_inff();
    }
    __syncthreads();
  }
}

__global__ __launch_bounds__(256) void zero_kernel(float4* __restrict__ out) {
  size_t i = (size_t)blockIdx.x * 256 + threadIdx.x;
  out[i] = make_float4(0.f, 0.f, 0.f, 0.f);
}

__global__ void zeroc_kernel(u32* __restrict__ c) {
  if (threadIdx.x < KM_ITERS + 1) c[threadIdx.x] = 0u;
}

__global__ __launch_bounds__(256) void scatter_kernel(const float* __restrict__ adj,
                                                      const int* __restrict__ iknn,
                                                      const int* __restrict__ labels,
                                                      float* __restrict__ out) {
  int idx = blockIdx.x * 256 + threadIdx.x;
  int i = idx >> 4;
  int col = iknn[idx];
  int m = 0;
#pragma unroll
  for (int r = 0; r < RR; ++r)
    m |= (labels[(size_t)r * NN + i] == labels[(size_t)r * NN + col]);
  size_t o = (size_t)i * NN + col;
  out[o] = adj[o] + (float)m;
}

extern "C" void kernel_launch(void* const* d_in, const int* in_sizes, int n_in,
                              void* d_out, int out_size, void* d_ws, size_t ws_size,
                              hipStream_t stream) {
  (void)in_sizes; (void)n_in; (void)out_size; (void)ws_size;
  const float* adj     = (const float*)d_in[0];
  const float* student = (const float*)d_in[1];
  const float* teacher = (const float*)d_in[2];
  float* out = (float*)d_out;

  char* p = (char*)d_ws;
  auto alloc = [&](size_t bytes) -> void* {
    void* q = (void*)p; p += (bytes + 255) & ~(size_t)255; return q;
  };
  double* centA  = (double*)alloc((size_t)RR * CC * DD * 8);
  double* centB  = (double*)alloc((size_t)RR * CC * DD * 8);
  float*  centF  = (float*) alloc((size_t)RR * CC * DD * 4);
  double* cnD    = (double*)alloc((size_t)RR * CC * 8);
  float*  cnF    = (float*) alloc((size_t)RR * CC * 4);
  u32*    bits1  = (u32*)   alloc((size_t)RR * NN * 4);
  u32*    bits2  = (u32*)   alloc((size_t)RR * NN * 4);
  u32*    prank  = (u32*)   alloc((size_t)RR * 4 * NN * 4);
  int*    v1     = (int*)   alloc((size_t)RR * NN * 4);
  int*    sel    = (int*)   alloc((size_t)RR * CC * 4);
  int*    labels = (int*)   alloc((size_t)RR * NN * 4);
  int*    bhist  = (int*)   alloc((size_t)RR * 32 * CC * 4);
  int*    boff   = (int*)   alloc((size_t)RR * 32 * CC * 4);
  int*    cstart = (int*)   alloc((size_t)RR * CC * 4);
  int*    cnt    = (int*)   alloc((size_t)RR * CC * 4);
  int*    rib    = (int*)   alloc((size_t)RR * NN * 4);
  int*    member = (int*)   alloc((size_t)RR * NN * 4);
  u32*    flags  = (u32*)   alloc((size_t)(KM_ITERS + 1) * FIXCAP * 4);
  u32*    counters = (u32*) alloc((size_t)(KM_ITERS + 1) * 4);
  int*    iknn   = (int*)   alloc((size_t)NN * TOPKK * 4);
  float*  simc   = (float*) alloc((size_t)CHUNK * NN * 4);

  zeroc_kernel<<<1, 32, 0, stream>>>(counters);

  // --- k-means init: JAX threefry choice(key, 8192, (64,), replace=False) ---
  rng_kernel<<<dim3(RR, 32), 256, 0, stream>>>(bits1, bits2);
  rankpart_kernel<<<dim3(RR, 32, 4), 256, 0, stream>>>(bits1, prank);
  scat1_kernel<<<dim3(RR, 32), 256, 0, stream>>>(prank, v1);
  rankpart_kernel<<<dim3(RR, 32, 4), 256, 0, stream>>>(bits2, prank);
  scat2_kernel<<<dim3(RR, 32), 256, 0, stream>>>(prank, v1, sel);
  init_cent_kernel<<<dim3(RR, CC), 256, 0, stream>>>(teacher, sel, centA, centF, cnD, cnF);

  // --- 20 Lloyd iterations: f32 assign + f64 fixup of marginal points ---
  double* cur = centA; double* nxt = centB;
  for (int it = 0; it < KM_ITERS; ++it) {
    assign_kernel<<<dim3(NN / 64, RR), 256, 0, stream>>>(teacher, centF, cnF, labels,
                                                         flags + (size_t)it * FIXCAP,
                                                         counters + it);
    fixup_kernel<<<64, 256, 0, stream>>>(teacher, cur, cnD,
                                         flags + (size_t)it * FIXCAP, counters + it, labels);
    hist_kernel<<<dim3(RR, 32), 256, 0, stream>>>(labels, bhist, rib);
    scan_kernel<<<RR, CC, 0, stream>>>(bhist, boff, cstart, cnt);
    fill_kernel<<<dim3(RR, 32), 256, 0, stream>>>(labels, rib, boff, cstart, member);
    update_kernel<<<dim3(RR, CC), 256, 0, stream>>>(teacher, member, cstart, cnt, cur, nxt,
                                                    centF, cnD, cnF);
    double* t = cur; cur = nxt; nxt = t;
  }
  assign_kernel<<<dim3(NN / 64, RR), 256, 0, stream>>>(teacher, centF, cnF, labels,
                                                       flags + (size_t)KM_ITERS * FIXCAP,
                                                       counters + KM_ITERS);
  fixup_kernel<<<64, 256, 0, stream>>>(teacher, cur, cnD,
                                       flags + (size_t)KM_ITERS * FIXCAP,
                                       counters + KM_ITERS, labels);

  // --- sim = student @ teacher.T (+10 I) in row chunks, then per-row top-16 ---
  for (int ch = 0; ch < NN / CHUNK; ++ch) {
    gemm_kernel<<<dim3(NN / 64, CHUNK / 64), 256, 0, stream>>>(student, teacher, simc,
                                                               ch * CHUNK);
    topk_kernel<<<CHUNK, 256, 0, stream>>>(simc, iknn, ch * CHUNK);
  }

  // --- pos = 0 everywhere; pos[i, knn] = adj + mask ---
  zero_kernel<<<(unsigned)((size_t)NN * NN / 4 / 256), 256, 0, stream>>>((float4*)out);
  scatter_kernel<<<NN * TOPKK / 256, 256, 0, stream>>>(adj, iknn, labels, out);
}

// Round 3
// 4892.834 us; speedup vs baseline: 1.2253x; 1.2042x over previous
//
#include <hip/hip_runtime.h>
#include <stdint.h>

typedef unsigned int u32;
typedef unsigned long long u64;

#define NN 8192
#define DD 512
#define CC 64            // NUM_CENTROIDS
#define RR 5             // NUM_KMEANS
#define KM_ITERS 20
#define TOPKK 16
#define CHUNK 1024       // sim row-chunk (bounds ws use to ~42 MB)
#define FIXCAP (RR * NN) // flag capacity per iteration
#define GAP_TH 0.05f     // f32 gap below which we re-decide in f64

// JAX PRNG derivation: 1 = threefry_partitionable (verified correct in R1).
#define JAX_PARTITIONABLE 1

// ---------------- Threefry-2x32, 20 rounds (matches jax/_src/prng.py) -------
__device__ __forceinline__ void tf2x32(u32 k0, u32 k1, u32 x0, u32 x1,
                                       u32& o0, u32& o1) {
  u32 ks2 = k0 ^ k1 ^ 0x1BD11BDAu;
  x0 += k0; x1 += k1;
#define TFR(r) { x0 += x1; x1 = (x1 << r) | (x1 >> (32 - r)); x1 ^= x0; }
  TFR(13) TFR(15) TFR(26) TFR(6)
  x0 += k1; x1 += ks2 + 1u;
  TFR(17) TFR(29) TFR(16) TFR(24)
  x0 += ks2; x1 += k0 + 2u;
  TFR(13) TFR(15) TFR(26) TFR(6)
  x0 += k0; x1 += k1 + 3u;
  TFR(17) TFR(29) TFR(16) TFR(24)
  x0 += k1; x1 += ks2 + 4u;
  TFR(13) TFR(15) TFR(26) TFR(6)
  x0 += ks2; x1 += k0 + 5u;
#undef TFR
  o0 = x0; o1 = x1;
}

__global__ __launch_bounds__(256) void rng_kernel(u32* __restrict__ bits1,
                                                  u32* __restrict__ bits2) {
  int r = blockIdx.x;
  int i = blockIdx.y * 256 + threadIdx.x;
#if JAX_PARTITIONABLE
  u32 rk0, rk1; tf2x32(0u, 1234u, 0u, (u32)r, rk0, rk1);
  u32 k10, k11, s10, s11, s20, s21;
  tf2x32(rk0, rk1, 0u, 0u, k10, k11);
  tf2x32(rk0, rk1, 0u, 1u, s10, s11);
  tf2x32(k10, k11, 0u, 1u, s20, s21);
  u32 a, b;
  tf2x32(s10, s11, 0u, (u32)i, a, b);
  bits1[r * NN + i] = a ^ b;
  tf2x32(s20, s21, 0u, (u32)i, a, b);
  bits2[r * NN + i] = a ^ b;
#else
  if (i >= NN / 2) return;
  u32 rk0, rk1; tf2x32(0u, 1234u, (u32)r, (u32)(r + RR), rk0, rk1);
  u32 e00, e01, e10, e11;
  tf2x32(rk0, rk1, 0u, 2u, e00, e01);
  tf2x32(rk0, rk1, 1u, 3u, e10, e11);
  u32 k10 = e00, k11 = e10, s10 = e01, s11 = e11;
  tf2x32(k10, k11, 0u, 2u, e00, e01);
  tf2x32(k10, k11, 1u, 3u, e10, e11);
  u32 s20 = e01, s21 = e11;
  u32 a, b;
  tf2x32(s10, s11, (u32)i, (u32)(i + NN / 2), a, b);
  bits1[r * NN + i] = a; bits1[r * NN + i + NN / 2] = b;
  tf2x32(s20, s21, (u32)i, (u32)(i + NN / 2), a, b);
  bits2[r * NN + i] = a; bits2[r * NN + i + NN / 2] = b;
#endif
}

// Partial stable-rank: key = (bits<<13)|j; count keys < mine in a 2048-j chunk.
__global__ __launch_bounds__(256) void rankpart_kernel(const u32* __restrict__ bits,
                                                       u32* __restrict__ prank) {
  __shared__ u64 sk[2048];
  int r = blockIdx.x, zc = blockIdx.z;
  const u32* bb = bits + (size_t)r * NN;
  int jbase = zc * 2048;
  for (int t = threadIdx.x; t < 2048; t += 256)
    sk[t] = ((u64)bb[jbase + t] << 13) | (u32)(jbase + t);
  __syncthreads();
  int i = blockIdx.y * 256 + threadIdx.x;
  u64 ki = ((u64)bb[i] << 13) | (u32)i;
  int cnt = 0;
#pragma unroll 8
  for (int j = 0; j < 2048; ++j) cnt += (int)(sk[j] < ki);
  prank[(size_t)(r * 4 + zc) * NN + i] = cnt;
}

__global__ __launch_bounds__(256) void scat1_kernel(const u32* __restrict__ prank,
                                                    int* __restrict__ vout) {
  int r = blockIdx.x;
  int i = blockIdx.y * 256 + threadIdx.x;
  int rank = prank[(size_t)(r * 4 + 0) * NN + i] + prank[(size_t)(r * 4 + 1) * NN + i] +
             prank[(size_t)(r * 4 + 2) * NN + i] + prank[(size_t)(r * 4 + 3) * NN + i];
  vout[(size_t)r * NN + rank] = i;
}

__global__ __launch_bounds__(256) void scat2_kernel(const u32* __restrict__ prank,
                                                    const int* __restrict__ v1,
                                                    int* __restrict__ sel) {
  int r = blockIdx.x;
  int i = blockIdx.y * 256 + threadIdx.x;
  int rank = prank[(size_t)(r * 4 + 0) * NN + i] + prank[(size_t)(r * 4 + 1) * NN + i] +
             prank[(size_t)(r * 4 + 2) * NN + i] + prank[(size_t)(r * 4 + 3) * NN + i];
  if (rank < CC) sel[r * CC + rank] = v1[(size_t)r * NN + i];
}

__device__ __forceinline__ double block_reduce_d(double s, double* red4) {
  int tid = threadIdx.x;
  for (int off = 32; off > 0; off >>= 1) s += __shfl_down(s, off, 64);
  if ((tid & 63) == 0) red4[tid >> 6] = s;
  __syncthreads();
  return red4[0] + red4[1] + red4[2] + red4[3];
}

__global__ __launch_bounds__(256) void init_cent_kernel(const float* __restrict__ X,
                                                        const int* __restrict__ sel,
                                                        double* __restrict__ centD,
                                                        float* __restrict__ centF,
                                                        double* __restrict__ cnD,
                                                        float* __restrict__ cnF) {
  __shared__ double red4[4];
  int r = blockIdx.x, c = blockIdx.y, t = threadIdx.x;
  int src = sel[r * CC + c];
  const float* xp = X + (size_t)src * DD;
  size_t o = (size_t)(r * CC + c) * DD;
  double va = (double)xp[t], vb = (double)xp[t + 256];
  centD[o + t] = va; centD[o + t + 256] = vb;
  centF[o + t] = (float)va; centF[o + t + 256] = (float)vb;
  double tot = block_reduce_d(va * va + vb * vb, red4);
  if (t == 0) { cnD[r * CC + c] = tot; cnF[r * CC + c] = (float)tot; }
}

// f32 assign with best/second gap tracking; marginal points flagged for f64 fixup.
__global__ __launch_bounds__(256) void assign_kernel(const float* __restrict__ X,
                                                     const float* __restrict__ centF,
                                                     const float* __restrict__ cnF,
                                                     int* __restrict__ labels,
                                                     u32* __restrict__ flags,
                                                     u32* __restrict__ counter) {
  __shared__ float Xs[64][68];
  __shared__ float Cs[64][68];
  int r = blockIdx.y;
  int rowBase = blockIdx.x * 64;
  int tid = threadIdx.x, tx = tid & 15, ty = tid >> 4;
  const float* cb = centF + (size_t)r * CC * DD;
  float acc[4][4] = {{0.f}};
  for (int kc = 0; kc < DD; kc += 64) {
    for (int l = 0; l < 4; ++l) {
      int idx4 = l * 256 + tid;
      int row = idx4 >> 4, k4 = (idx4 & 15) << 2;
      *(float4*)&Xs[row][k4] = *(const float4*)(X + (size_t)(rowBase + row) * DD + kc + k4);
      *(float4*)&Cs[row][k4] = *(const float4*)(cb + (size_t)row * DD + kc + k4);
    }
    __syncthreads();
    for (int k = 0; k < 64; k += 4) {
      float4 av[4], bv[4];
      av[0] = *(float4*)&Xs[ty][k];      av[1] = *(float4*)&Xs[ty + 16][k];
      av[2] = *(float4*)&Xs[ty + 32][k]; av[3] = *(float4*)&Xs[ty + 48][k];
      bv[0] = *(float4*)&Cs[tx][k];      bv[1] = *(float4*)&Cs[tx + 16][k];
      bv[2] = *(float4*)&Cs[tx + 32][k]; bv[3] = *(float4*)&Cs[tx + 48][k];
#pragma unroll
      for (int i = 0; i < 4; ++i)
#pragma unroll
        for (int j = 0; j < 4; ++j)
          acc[i][j] += av[i].x * bv[j].x + av[i].y * bv[j].y +
                       av[i].z * bv[j].z + av[i].w * bv[j].w;
    }
    __syncthreads();
  }
  float* dmat = &Cs[0][0];   // reuse Cs as [64][68] distance matrix
#pragma unroll
  for (int i = 0; i < 4; ++i)
#pragma unroll
    for (int j = 0; j < 4; ++j)
      dmat[(size_t)(ty + 16 * i) * 68 + (tx + 16 * j)] =
          cnF[r * CC + tx + 16 * j] - 2.0f * acc[i][j];
  __syncthreads();
  if (tid < 64) {
    const float* dr = dmat + (size_t)tid * 68;
    float best = dr[0], second = 3.4e38f; int bi = 0;
    for (int c = 1; c < CC; ++c) {
      float v = dr[c];
      if (v < best) { second = best; best = v; bi = c; }
      else if (v < second) second = v;
    }
    labels[(size_t)r * NN + rowBase + tid] = bi;
    if (second - best < GAP_TH) {
      u32 idx = atomicAdd(counter, 1u);
      flags[idx] = (u32)(r * NN + rowBase + tid);
    }
  }
}

// Exact f64 re-decision for flagged (marginal) points. Fixed 64-block grid.
__global__ __launch_bounds__(256) void fixup_kernel(const float* __restrict__ X,
                                                    const double* __restrict__ centD,
                                                    const double* __restrict__ cnD,
                                                    const u32* __restrict__ flags,
                                                    const u32* __restrict__ counter,
                                                    int* __restrict__ labels) {
  __shared__ double darr[CC];
  int n = (int)*counter;
  int tid = threadIdx.x, c = tid >> 2, sub = tid & 3;
  for (int f = blockIdx.x; f < n; f += gridDim.x) {
    u32 pk = flags[f];
    int r = pk >> 13, i = pk & (NN - 1);
    const float* x = X + (size_t)i * DD + sub * 128;
    const double* cp = centD + (size_t)(r * CC + c) * DD + sub * 128;
    double s = 0.0;
    for (int k = 0; k < 128; ++k) s += (double)x[k] * cp[k];
    s += __shfl_down(s, 2, 64);
    s += __shfl_down(s, 1, 64);
    if (sub == 0) darr[c] = cnD[r * CC + c] - 2.0 * s;
    __syncthreads();
    if (tid == 0) {
      double best = darr[0]; int bi = 0;
      for (int cc = 1; cc < CC; ++cc) { double v = darr[cc]; if (v < best) { best = v; bi = cc; } }
      labels[(size_t)r * NN + i] = bi;
    }
    __syncthreads();
  }
}

__global__ __launch_bounds__(256) void hist_kernel(const int* __restrict__ labels,
                                                   int* __restrict__ bhist,
                                                   int* __restrict__ rib) {
  __shared__ int ls[256];
  __shared__ int h[CC];
  int r = blockIdx.x, blk = blockIdx.y, tid = threadIdx.x;
  int i = blk * 256 + tid;
  int lab = labels[(size_t)r * NN + i];
  ls[tid] = lab;
  if (tid < CC) h[tid] = 0;
  __syncthreads();
  atomicAdd(&h[lab], 1);
  int rk = 0;
  for (int j = 0; j < tid; ++j) rk += (ls[j] == lab);
  rib[(size_t)r * NN + i] = rk;
  __syncthreads();
  if (tid < CC) bhist[(size_t)(r * 32 + blk) * CC + tid] = h[tid];
}

__global__ void scan_kernel(const int* __restrict__ bhist, int* __restrict__ boff,
                            int* __restrict__ cstart, int* __restrict__ cnt) {
  int r = blockIdx.x, c = threadIdx.x;
  int tot = 0;
  for (int b = 0; b < 32; ++b) {
    boff[(size_t)(r * 32 + b) * CC + c] = tot;
    tot += bhist[(size_t)(r * 32 + b) * CC + c];
  }
  cnt[r * CC + c] = tot;
  __shared__ int s[CC];
  s[c] = tot;
  __syncthreads();
  if (c == 0) { int run = 0; for (int q = 0; q < CC; ++q) { int t = s[q]; s[q] = run; run += t; } }
  __syncthreads();
  cstart[r * CC + c] = s[c];
}

__global__ __launch_bounds__(256) void fill_kernel(const int* __restrict__ labels,
                                                   const int* __restrict__ rib,
                                                   const int* __restrict__ boff,
                                                   const int* __restrict__ cstart,
                                                   int* __restrict__ member) {
  int r = blockIdx.x, blk = blockIdx.y, tid = threadIdx.x;
  int i = blk * 256 + tid;
  int lab = labels[(size_t)r * NN + i];
  int pos = cstart[r * CC + lab] + boff[(size_t)(r * 32 + blk) * CC + lab] +
            rib[(size_t)r * NN + i];
  member[(size_t)r * NN + pos] = i;
}

// Parallel deterministic centroid update: grid (RR, CC, 8 dim-chunks of 64).
// 4 waves/block = 4 contiguous member-list quarters, 4-accumulator ILP each,
// fixed combine tree -> run-to-run deterministic f64.
__global__ __launch_bounds__(256) void update_kernel(const float* __restrict__ X,
                                                     const int* __restrict__ member,
                                                     const int* __restrict__ cstart,
                                                     const int* __restrict__ cnt,
                                                     const double* __restrict__ centOld,
                                                     double* __restrict__ centNew,
                                                     float* __restrict__ centF) {
  __shared__ double part[4][64];
  int r = blockIdx.x, c = blockIdx.y, dchunk = blockIdx.z;
  int tid = threadIdx.x;
  int d = dchunk * 64 + (tid & 63);
  int lane = tid >> 6;                  // wave id 0..3
  int n = cnt[r * CC + c];
  int st = cstart[r * CC + c];
  const int* mem = member + (size_t)r * NN + st;
  int n4 = (n + 3) >> 2;
  int lo = lane * n4;
  int hi = min(n, lo + n4);
  double s0 = 0, s1 = 0, s2 = 0, s3 = 0;
  int m = lo;
  for (; m + 3 < hi; m += 4) {
    s0 += (double)X[(size_t)mem[m + 0] * DD + d];
    s1 += (double)X[(size_t)mem[m + 1] * DD + d];
    s2 += (double)X[(size_t)mem[m + 2] * DD + d];
    s3 += (double)X[(size_t)mem[m + 3] * DD + d];
  }
  for (; m < hi; ++m) s0 += (double)X[(size_t)mem[m] * DD + d];
  part[lane][tid & 63] = (s0 + s1) + (s2 + s3);
  __syncthreads();
  if (tid < 64) {
    double tot = (part[0][tid] + part[1][tid]) + (part[2][tid] + part[3][tid]);
    size_t o = (size_t)(r * CC + c) * DD + dchunk * 64 + tid;
    double va = (n > 0) ? tot / (double)n : centOld[o];
    centNew[o] = va;
    centF[o] = (float)va;
  }
}

// Recompute centroid squared norms from centNew (same tree as init_cent).
__global__ __launch_bounds__(256) void norm_kernel(const double* __restrict__ centNew,
                                                   double* __restrict__ cnD,
                                                   float* __restrict__ cnF) {
  __shared__ double red4[4];
  int r = blockIdx.x, c = blockIdx.y, t = threadIdx.x;
  size_t o = (size_t)(r * CC + c) * DD;
  double va = centNew[o + t], vb = centNew[o + t + 256];
  double tot = block_reduce_d(va * va + vb * vb, red4);
  if (t == 0) { cnD[r * CC + c] = tot; cnF[r * CC + c] = (float)tot; }
}

// sim chunk GEMM: f32 products, f32 per-64-k chunk accumulate, f64 chunk combine.
__global__ __launch_bounds__(256) void gemm_kernel(const float* __restrict__ S,
                                                   const float* __restrict__ T,
                                                   float* __restrict__ sim,
                                                   int rowChunk) {
  __shared__ float As[64][68];
  __shared__ float Bs[64][68];
  int tid = threadIdx.x, tx = tid & 15, ty = tid >> 4;
  int rowBase = rowChunk + blockIdx.y * 64;
  int colBase = blockIdx.x * 64;
  float  a32[4][4] = {{0.f}};
  double a64[4][4] = {{0.0}};
  for (int kc = 0; kc < DD; kc += 64) {
    for (int l = 0; l < 4; ++l) {
      int idx4 = l * 256 + tid;
      int row = idx4 >> 4, k4 = (idx4 & 15) << 2;
      *(float4*)&As[row][k4] = *(const float4*)(S + (size_t)(rowBase + row) * DD + kc + k4);
      *(float4*)&Bs[row][k4] = *(const float4*)(T + (size_t)(colBase + row) * DD + kc + k4);
    }
    __syncthreads();
    for (int k = 0; k < 64; k += 4) {
      float4 av[4], bv[4];
      av[0] = *(float4*)&As[ty][k];      av[1] = *(float4*)&As[ty + 16][k];
      av[2] = *(float4*)&As[ty + 32][k]; av[3] = *(float4*)&As[ty + 48][k];
      bv[0] = *(float4*)&Bs[tx][k];      bv[1] = *(float4*)&Bs[tx + 16][k];
      bv[2] = *(float4*)&Bs[tx + 32][k]; bv[3] = *(float4*)&Bs[tx + 48][k];
#pragma unroll
      for (int i = 0; i < 4; ++i)
#pragma unroll
        for (int j = 0; j < 4; ++j)
          a32[i][j] += av[i].x * bv[j].x + av[i].y * bv[j].y +
                       av[i].z * bv[j].z + av[i].w * bv[j].w;
    }
    __syncthreads();
#pragma unroll
    for (int i = 0; i < 4; ++i)
#pragma unroll
      for (int j = 0; j < 4; ++j) { a64[i][j] += (double)a32[i][j]; a32[i][j] = 0.f; }
  }
#pragma unroll
  for (int i = 0; i < 4; ++i)
#pragma unroll
    for (int j = 0; j < 4; ++j) {
      int lrow = blockIdx.y * 64 + ty + 16 * i;
      int gcol = colBase + tx + 16 * j;
      int grow = rowChunk + lrow;
      float v = (float)a64[i][j];
      if (grow == gcol) v += 10.0f;
      sim[(size_t)lrow * NN + gcol] = v;
    }
}

__global__ __launch_bounds__(256) void topk_kernel(const float* __restrict__ sim,
                                                   int* __restrict__ iknn,
                                                   int rowChunk) {
  __shared__ float rowv[NN];
  __shared__ u64 red[4];
  int blk = blockIdx.x;
  int tid = threadIdx.x;
  const float* rp = sim + (size_t)blk * NN;
  for (int t = tid; t < NN; t += 256) rowv[t] = rp[t];
  __syncthreads();
  int grow = rowChunk + blk;
  for (int k = 0; k < TOPKK; ++k) {
    u64 best = 0;
    for (int t = tid; t < NN; t += 256) {
      float v = rowv[t];
      u32 u = __float_as_uint(v);
      u = (u & 0x80000000u) ? ~u : (u | 0x80000000u);
      u64 key = ((u64)u << 32) | (u32)(NN - 1 - t);
      best = key > best ? key : best;
    }
    for (int off = 32; off > 0; off >>= 1) {
      u32 lo = (u32)best, hi = (u32)(best >> 32);
      lo = __shfl_down(lo, off, 64); hi = __shfl_down(hi, off, 64);
      u64 o = ((u64)hi << 32) | lo;
      best = o > best ? o : best;
    }
    if ((tid & 63) == 0) red[tid >> 6] = best;
    __syncthreads();
    if (tid == 0) {
      u64 b = red[0];
      for (int w = 1; w < 4; ++w) b = red[w] > b ? red[w] : b;
      int t = (NN - 1) - (int)(b & 0xFFFFFFFFu);
      iknn[(size_t)grow * TOPKK + k] = t;
      rowv[t] = -__builtin_inff();
    }
    __syncthreads();
  }
}

__global__ __launch_bounds__(256) void zero_kernel(float4* __restrict__ out) {
  size_t i = (size_t)blockIdx.x * 256 + threadIdx.x;
  out[i] = make_float4(0.f, 0.f, 0.f, 0.f);
}

__global__ void zeroc_kernel(u32* __restrict__ c) {
  if (threadIdx.x < KM_ITERS + 1) c[threadIdx.x] = 0u;
}

__global__ __launch_bounds__(256) void scatter_kernel(const float* __restrict__ adj,
                                                      const int* __restrict__ iknn,
                                                      const int* __restrict__ labels,
                                                      float* __restrict__ out) {
  int idx = blockIdx.x * 256 + threadIdx.x;
  int i = idx >> 4;
  int col = iknn[idx];
  int m = 0;
#pragma unroll
  for (int r = 0; r < RR; ++r)
    m |= (labels[(size_t)r * NN + i] == labels[(size_t)r * NN + col]);
  size_t o = (size_t)i * NN + col;
  out[o] = adj[o] + (float)m;
}

extern "C" void kernel_launch(void* const* d_in, const int* in_sizes, int n_in,
                              void* d_out, int out_size, void* d_ws, size_t ws_size,
                              hipStream_t stream) {
  (void)in_sizes; (void)n_in; (void)out_size; (void)ws_size;
  const float* adj     = (const float*)d_in[0];
  const float* student = (const float*)d_in[1];
  const float* teacher = (const float*)d_in[2];
  float* out = (float*)d_out;

  char* p = (char*)d_ws;
  auto alloc = [&](size_t bytes) -> void* {
    void* q = (void*)p; p += (bytes + 255) & ~(size_t)255; return q;
  };
  double* centA  = (double*)alloc((size_t)RR * CC * DD * 8);
  double* centB  = (double*)alloc((size_t)RR * CC * DD * 8);
  float*  centF  = (float*) alloc((size_t)RR * CC * DD * 4);
  double* cnD    = (double*)alloc((size_t)RR * CC * 8);
  float*  cnF    = (float*) alloc((size_t)RR * CC * 4);
  u32*    bits1  = (u32*)   alloc((size_t)RR * NN * 4);
  u32*    bits2  = (u32*)   alloc((size_t)RR * NN * 4);
  u32*    prank  = (u32*)   alloc((size_t)RR * 4 * NN * 4);
  int*    v1     = (int*)   alloc((size_t)RR * NN * 4);
  int*    sel    = (int*)   alloc((size_t)RR * CC * 4);
  int*    labels = (int*)   alloc((size_t)RR * NN * 4);
  int*    bhist  = (int*)   alloc((size_t)RR * 32 * CC * 4);
  int*    boff   = (int*)   alloc((size_t)RR * 32 * CC * 4);
  int*    cstart = (int*)   alloc((size_t)RR * CC * 4);
  int*    cnt    = (int*)   alloc((size_t)RR * CC * 4);
  int*    rib    = (int*)   alloc((size_t)RR * NN * 4);
  int*    member = (int*)   alloc((size_t)RR * NN * 4);
  u32*    flags  = (u32*)   alloc((size_t)(KM_ITERS + 1) * FIXCAP * 4);
  u32*    counters = (u32*) alloc((size_t)(KM_ITERS + 1) * 4);
  int*    iknn   = (int*)   alloc((size_t)NN * TOPKK * 4);
  float*  simc   = (float*) alloc((size_t)CHUNK * NN * 4);

  zeroc_kernel<<<1, 32, 0, stream>>>(counters);

  // --- k-means init: JAX threefry choice(key, 8192, (64,), replace=False) ---
  rng_kernel<<<dim3(RR, 32), 256, 0, stream>>>(bits1, bits2);
  rankpart_kernel<<<dim3(RR, 32, 4), 256, 0, stream>>>(bits1, prank);
  scat1_kernel<<<dim3(RR, 32), 256, 0, stream>>>(prank, v1);
  rankpart_kernel<<<dim3(RR, 32, 4), 256, 0, stream>>>(bits2, prank);
  scat2_kernel<<<dim3(RR, 32), 256, 0, stream>>>(prank, v1, sel);
  init_cent_kernel<<<dim3(RR, CC), 256, 0, stream>>>(teacher, sel, centA, centF, cnD, cnF);

  // --- 20 Lloyd iterations: f32 assign + f64 fixup of marginal points ---
  double* cur = centA; double* nxt = centB;
  for (int it = 0; it < KM_ITERS; ++it) {
    assign_kernel<<<dim3(NN / 64, RR), 256, 0, stream>>>(teacher, centF, cnF, labels,
                                                         flags + (size_t)it * FIXCAP,
                                                         counters + it);
    fixup_kernel<<<64, 256, 0, stream>>>(teacher, cur, cnD,
                                         flags + (size_t)it * FIXCAP, counters + it, labels);
    hist_kernel<<<dim3(RR, 32), 256, 0, stream>>>(labels, bhist, rib);
    scan_kernel<<<RR, CC, 0, stream>>>(bhist, boff, cstart, cnt);
    fill_kernel<<<dim3(RR, 32), 256, 0, stream>>>(labels, rib, boff, cstart, member);
    update_kernel<<<dim3(RR, CC, 8), 256, 0, stream>>>(teacher, member, cstart, cnt, cur, nxt,
                                                       centF);
    norm_kernel<<<dim3(RR, CC), 256, 0, stream>>>(nxt, cnD, cnF);
    double* t = cur; cur = nxt; nxt = t;
  }
  assign_kernel<<<dim3(NN / 64, RR), 256, 0, stream>>>(teacher, centF, cnF, labels,
                                                       flags + (size_t)KM_ITERS * FIXCAP,
                                                       counters + KM_ITERS);
  fixup_kernel<<<64, 256, 0, stream>>>(teacher, cur, cnD,
                                       flags + (size_t)KM_ITERS * FIXCAP,
                                       counters + KM_ITERS, labels);

  // --- sim = student @ teacher.T (+10 I) in row chunks, then per-row top-16 ---
  for (int ch = 0; ch < NN / CHUNK; ++ch) {
    gemm_kernel<<<dim3(NN / 64, CHUNK / 64), 256, 0, stream>>>(student, teacher, simc,
                                                               ch * CHUNK);
    topk_kernel<<<CHUNK, 256, 0, stream>>>(simc, iknn, ch * CHUNK);
  }

  // --- pos = 0 everywhere; pos[i, knn] = adj + mask ---
  zero_kernel<<<(unsigned)((size_t)NN * NN / 4 / 256), 256, 0, stream>>>((float4*)out);
  scatter_kernel<<<NN * TOPKK / 256, 256, 0, stream>>>(adj, iknn, labels, out);
}

// Round 4
// 3493.979 us; speedup vs baseline: 1.7158x; 1.4004x over previous
//
#include <hip/hip_runtime.h>
#include <stdint.h>

typedef unsigned int u32;
typedef unsigned long long u64;
typedef __attribute__((ext_vector_type(8))) short short8;
typedef __attribute__((ext_vector_type(4))) float f32x4;

#define NN 8192
#define DD 512
#define CC 64            // NUM_CENTROIDS
#define RR 5             // NUM_KMEANS
#define KM_ITERS 20
#define TOPKK 16
#define CHUNK 1024       // sim row-chunk
#define FIXCAP (RR * NN) // flag capacity per iteration
#define GAP_TH 0.05f     // assign: f32 gap below which we re-decide in f64
#define FLAGTH 0.02f     // topk: margin16-17 below which row is resolved exactly
#define BAND_TH 0.01f    // resolve: band half-width around val16
#define TKCAP 2048       // per-chunk resolve-record capacity

#define MFMA_BF16 __builtin_amdgcn_mfma_f32_16x16x32_bf16

// ---------------- Threefry-2x32, 20 rounds (matches jax/_src/prng.py) -------
__device__ __forceinline__ void tf2x32(u32 k0, u32 k1, u32 x0, u32 x1,
                                       u32& o0, u32& o1) {
  u32 ks2 = k0 ^ k1 ^ 0x1BD11BDAu;
  x0 += k0; x1 += k1;
#define TFR(r) { x0 += x1; x1 = (x1 << r) | (x1 >> (32 - r)); x1 ^= x0; }
  TFR(13) TFR(15) TFR(26) TFR(6)
  x0 += k1; x1 += ks2 + 1u;
  TFR(17) TFR(29) TFR(16) TFR(24)
  x0 += ks2; x1 += k0 + 2u;
  TFR(13) TFR(15) TFR(26) TFR(6)
  x0 += k0; x1 += k1 + 3u;
  TFR(17) TFR(29) TFR(16) TFR(24)
  x0 += k1; x1 += ks2 + 4u;
  TFR(13) TFR(15) TFR(26) TFR(6)
  x0 += ks2; x1 += k0 + 5u;
#undef TFR
  o0 = x0; o1 = x1;
}

__global__ __launch_bounds__(256) void rng_kernel(u32* __restrict__ bits1,
                                                  u32* __restrict__ bits2) {
  int r = blockIdx.x;
  int i = blockIdx.y * 256 + threadIdx.x;
  // threefry_partitionable derivation (verified R1)
  u32 rk0, rk1; tf2x32(0u, 1234u, 0u, (u32)r, rk0, rk1);
  u32 k10, k11, s10, s11, s20, s21;
  tf2x32(rk0, rk1, 0u, 0u, k10, k11);
  tf2x32(rk0, rk1, 0u, 1u, s10, s11);
  tf2x32(k10, k11, 0u, 1u, s20, s21);
  u32 a, b;
  tf2x32(s10, s11, 0u, (u32)i, a, b);
  bits1[r * NN + i] = a ^ b;
  tf2x32(s20, s21, 0u, (u32)i, a, b);
  bits2[r * NN + i] = a ^ b;
}

__global__ __launch_bounds__(256) void rankpart_kernel(const u32* __restrict__ bits,
                                                       u32* __restrict__ prank) {
  __shared__ u64 sk[2048];
  int r = blockIdx.x, zc = blockIdx.z;
  const u32* bb = bits + (size_t)r * NN;
  int jbase = zc * 2048;
  for (int t = threadIdx.x; t < 2048; t += 256)
    sk[t] = ((u64)bb[jbase + t] << 13) | (u32)(jbase + t);
  __syncthreads();
  int i = blockIdx.y * 256 + threadIdx.x;
  u64 ki = ((u64)bb[i] << 13) | (u32)i;
  int cnt = 0;
#pragma unroll 8
  for (int j = 0; j < 2048; ++j) cnt += (int)(sk[j] < ki);
  prank[(size_t)(r * 4 + zc) * NN + i] = cnt;
}

__global__ __launch_bounds__(256) void scat1_kernel(const u32* __restrict__ prank,
                                                    int* __restrict__ vout) {
  int r = blockIdx.x;
  int i = blockIdx.y * 256 + threadIdx.x;
  int rank = prank[(size_t)(r * 4 + 0) * NN + i] + prank[(size_t)(r * 4 + 1) * NN + i] +
             prank[(size_t)(r * 4 + 2) * NN + i] + prank[(size_t)(r * 4 + 3) * NN + i];
  vout[(size_t)r * NN + rank] = i;
}

__global__ __launch_bounds__(256) void scat2_kernel(const u32* __restrict__ prank,
                                                    const int* __restrict__ v1,
                                                    int* __restrict__ sel) {
  int r = blockIdx.x;
  int i = blockIdx.y * 256 + threadIdx.x;
  int rank = prank[(size_t)(r * 4 + 0) * NN + i] + prank[(size_t)(r * 4 + 1) * NN + i] +
             prank[(size_t)(r * 4 + 2) * NN + i] + prank[(size_t)(r * 4 + 3) * NN + i];
  if (rank < CC) sel[r * CC + rank] = v1[(size_t)r * NN + i];
}

__device__ __forceinline__ double block_reduce_d(double s, double* red4) {
  int tid = threadIdx.x;
  for (int off = 32; off > 0; off >>= 1) s += __shfl_down(s, off, 64);
  if ((tid & 63) == 0) red4[tid >> 6] = s;
  __syncthreads();
  return red4[0] + red4[1] + red4[2] + red4[3];
}

__global__ __launch_bounds__(256) void init_cent_kernel(const float* __restrict__ X,
                                                        const int* __restrict__ sel,
                                                        double* __restrict__ centD,
                                                        float* __restrict__ centF,
                                                        double* __restrict__ cnD,
                                                        float* __restrict__ cnF) {
  __shared__ double red4[4];
  int r = blockIdx.x, c = blockIdx.y, t = threadIdx.x;
  int src = sel[r * CC + c];
  const float* xp = X + (size_t)src * DD;
  size_t o = (size_t)(r * CC + c) * DD;
  double va = (double)xp[t], vb = (double)xp[t + 256];
  centD[o + t] = va; centD[o + t + 256] = vb;
  centF[o + t] = (float)va; centF[o + t + 256] = (float)vb;
  double tot = block_reduce_d(va * va + vb * vb, red4);
  if (t == 0) { cnD[r * CC + c] = tot; cnF[r * CC + c] = (float)tot; }
}

// -------- bf16 split helpers --------
__device__ __forceinline__ u32 bf16rne(float a) {
  u32 ab = __float_as_uint(a);
  return (ab + 0x7FFFu + ((ab >> 16) & 1u)) >> 16;
}
__device__ __forceinline__ void splitf(float a, unsigned short& hi, unsigned short& lo) {
  u32 h = bf16rne(a);
  float hf = __uint_as_float(h << 16);
  hi = (unsigned short)h;
  lo = (unsigned short)bf16rne(a - hf);
}

// Split an f32 array into hi/lo bf16 arrays. 8 elements per thread.
__global__ __launch_bounds__(256) void split_kernel(const float* __restrict__ in,
                                                    unsigned short* __restrict__ hi,
                                                    unsigned short* __restrict__ lo) {
  size_t base = ((size_t)blockIdx.x * 256 + threadIdx.x) * 8;
  float4 v0 = *(const float4*)(in + base);
  float4 v1 = *(const float4*)(in + base + 4);
  float vv[8] = {v0.x, v0.y, v0.z, v0.w, v1.x, v1.y, v1.z, v1.w};
  unsigned short h[8], l[8];
#pragma unroll
  for (int j = 0; j < 8; ++j) splitf(vv[j], h[j], l[j]);
  uint4 hv, lv;
  hv.x = h[0] | ((u32)h[1] << 16); hv.y = h[2] | ((u32)h[3] << 16);
  hv.z = h[4] | ((u32)h[5] << 16); hv.w = h[6] | ((u32)h[7] << 16);
  lv.x = l[0] | ((u32)l[1] << 16); lv.y = l[2] | ((u32)l[3] << 16);
  lv.z = l[4] | ((u32)l[5] << 16); lv.w = l[6] | ((u32)l[7] << 16);
  *(uint4*)(hi + base) = hv;
  *(uint4*)(lo + base) = lv;
}

// MFMA assign: dist = ||c||^2 - 2 x.c via bf16x3 split; gap-guard -> f64 fixup.
// grid (NN/64, RR), 256 thr = 4 waves; wave w: rows w*16..w*16+15, all 64 cents.
__global__ __launch_bounds__(256) void assign_kernel(const unsigned short* __restrict__ XH,
                                                     const unsigned short* __restrict__ XL,
                                                     const unsigned short* __restrict__ CHg,
                                                     const unsigned short* __restrict__ CLg,
                                                     const float* __restrict__ cnF,
                                                     int* __restrict__ labels,
                                                     u32* __restrict__ flags,
                                                     u32* __restrict__ counter) {
  __shared__ unsigned short Xh[64 * 40], Xl[64 * 40], Ch[64 * 40], Cl[64 * 40];
  __shared__ float dmat[64 * 68];
  int r = blockIdx.y;
  int rowBase = blockIdx.x * 64;
  int tid = threadIdx.x;
  int wid = tid >> 6, lane = tid & 63, m = lane & 15, q = lane >> 4;
  int srow = tid >> 2, sq = tid & 3;          // staging: one 16B seg per array
  const unsigned short* xh = XH + (size_t)(rowBase + srow) * DD + sq * 8;
  const unsigned short* xl = XL + (size_t)(rowBase + srow) * DD + sq * 8;
  const unsigned short* ch = CHg + ((size_t)r * CC + srow) * DD + sq * 8;
  const unsigned short* cl = CLg + ((size_t)r * CC + srow) * DD + sq * 8;
  int soff = srow * 40 + sq * 8;
  f32x4 acc[4] = {};
  for (int kc = 0; kc < DD; kc += 32) {
    *(uint4*)&Xh[soff] = *(const uint4*)(xh + kc);
    *(uint4*)&Xl[soff] = *(const uint4*)(xl + kc);
    *(uint4*)&Ch[soff] = *(const uint4*)(ch + kc);
    *(uint4*)&Cl[soff] = *(const uint4*)(cl + kc);
    __syncthreads();
    short8 ah = *(short8*)&Xh[(wid * 16 + m) * 40 + q * 8];
    short8 al = *(short8*)&Xl[(wid * 16 + m) * 40 + q * 8];
#pragma unroll
    for (int nt = 0; nt < 4; ++nt) {
      short8 bh = *(short8*)&Ch[(nt * 16 + m) * 40 + q * 8];
      short8 bl = *(short8*)&Cl[(nt * 16 + m) * 40 + q * 8];
      acc[nt] = MFMA_BF16(ah, bh, acc[nt], 0, 0, 0);
      acc[nt] = MFMA_BF16(ah, bl, acc[nt], 0, 0, 0);
      acc[nt] = MFMA_BF16(al, bh, acc[nt], 0, 0, 0);
    }
    __syncthreads();
  }
#pragma unroll
  for (int nt = 0; nt < 4; ++nt) {
    float cn = cnF[r * CC + nt * 16 + m];
#pragma unroll
    for (int reg = 0; reg < 4; ++reg)
      dmat[(wid * 16 + q * 4 + reg) * 68 + nt * 16 + m] = cn - 2.0f * acc[nt][reg];
  }
  __syncthreads();
  if (tid < 64) {
    const float* dr = dmat + (size_t)tid * 68;
    float best = dr[0], second = 3.4e38f; int bi = 0;
    for (int c = 1; c < CC; ++c) {
      float v = dr[c];
      if (v < best) { second = best; best = v; bi = c; }
      else if (v < second) second = v;
    }
    labels[(size_t)r * NN + rowBase + tid] = bi;
    if (second - best < GAP_TH) {
      u32 idx = atomicAdd(counter, 1u);
      if (idx < FIXCAP) flags[idx] = (u32)(r * NN + rowBase + tid);
    }
  }
}

// Exact f64 re-decision for flagged (marginal) points.
__global__ __launch_bounds__(256) void fixup_kernel(const float* __restrict__ X,
                                                    const double* __restrict__ centD,
                                                    const double* __restrict__ cnD,
                                                    const u32* __restrict__ flags,
                                                    const u32* __restrict__ counter,
                                                    int* __restrict__ labels) {
  __shared__ double darr[CC];
  int n = (int)*counter; if (n > FIXCAP) n = FIXCAP;
  int tid = threadIdx.x, c = tid >> 2, sub = tid & 3;
  for (int f = blockIdx.x; f < n; f += gridDim.x) {
    u32 pk = flags[f];
    int r = pk >> 13, i = pk & (NN - 1);
    const float* x = X + (size_t)i * DD + sub * 128;
    const double* cp = centD + (size_t)(r * CC + c) * DD + sub * 128;
    double s = 0.0;
    for (int k = 0; k < 128; ++k) s += (double)x[k] * cp[k];
    s += __shfl_down(s, 2, 64);
    s += __shfl_down(s, 1, 64);
    if (sub == 0) darr[c] = cnD[r * CC + c] - 2.0 * s;
    __syncthreads();
    if (tid == 0) {
      double best = darr[0]; int bi = 0;
      for (int cc = 1; cc < CC; ++cc) { double v = darr[cc]; if (v < best) { best = v; bi = cc; } }
      labels[(size_t)r * NN + i] = bi;
    }
    __syncthreads();
  }
}

__global__ __launch_bounds__(256) void hist_kernel(const int* __restrict__ labels,
                                                   int* __restrict__ bhist,
                                                   int* __restrict__ rib) {
  __shared__ int ls[256];
  __shared__ int h[CC];
  int r = blockIdx.x, blk = blockIdx.y, tid = threadIdx.x;
  int i = blk * 256 + tid;
  int lab = labels[(size_t)r * NN + i];
  ls[tid] = lab;
  if (tid < CC) h[tid] = 0;
  __syncthreads();
  atomicAdd(&h[lab], 1);
  int rk = 0;
  for (int j = 0; j < tid; ++j) rk += (ls[j] == lab);
  rib[(size_t)r * NN + i] = rk;
  __syncthreads();
  if (tid < CC) bhist[(size_t)(r * 32 + blk) * CC + tid] = h[tid];
}

__global__ void scan_kernel(const int* __restrict__ bhist, int* __restrict__ boff,
                            int* __restrict__ cstart, int* __restrict__ cnt) {
  int r = blockIdx.x, c = threadIdx.x;
  int tot = 0;
  for (int b = 0; b < 32; ++b) {
    boff[(size_t)(r * 32 + b) * CC + c] = tot;
    tot += bhist[(size_t)(r * 32 + b) * CC + c];
  }
  cnt[r * CC + c] = tot;
  __shared__ int s[CC];
  s[c] = tot;
  __syncthreads();
  if (c == 0) { int run = 0; for (int q = 0; q < CC; ++q) { int t = s[q]; s[q] = run; run += t; } }
  __syncthreads();
  cstart[r * CC + c] = s[c];
}

__global__ __launch_bounds__(256) void fill_kernel(const int* __restrict__ labels,
                                                   const int* __restrict__ rib,
                                                   const int* __restrict__ boff,
                                                   const int* __restrict__ cstart,
                                                   int* __restrict__ member) {
  int r = blockIdx.x, blk = blockIdx.y, tid = threadIdx.x;
  int i = blk * 256 + tid;
  int lab = labels[(size_t)r * NN + i];
  int pos = cstart[r * CC + lab] + boff[(size_t)(r * 32 + blk) * CC + lab] +
            rib[(size_t)r * NN + i];
  member[(size_t)r * NN + pos] = i;
}

__global__ __launch_bounds__(256) void update_kernel(const float* __restrict__ X,
                                                     const int* __restrict__ member,
                                                     const int* __restrict__ cstart,
                                                     const int* __restrict__ cnt,
                                                     const double* __restrict__ centOld,
                                                     double* __restrict__ centNew,
                                                     float* __restrict__ centF) {
  __shared__ double part[4][64];
  int r = blockIdx.x, c = blockIdx.y, dchunk = blockIdx.z;
  int tid = threadIdx.x;
  int d = dchunk * 64 + (tid & 63);
  int lane = tid >> 6;
  int n = cnt[r * CC + c];
  int st = cstart[r * CC + c];
  const int* mem = member + (size_t)r * NN + st;
  int n4 = (n + 3) >> 2;
  int lo = lane * n4;
  int hi = min(n, lo + n4);
  double s0 = 0, s1 = 0, s2 = 0, s3 = 0;
  int m = lo;
  for (; m + 3 < hi; m += 4) {
    s0 += (double)X[(size_t)mem[m + 0] * DD + d];
    s1 += (double)X[(size_t)mem[m + 1] * DD + d];
    s2 += (double)X[(size_t)mem[m + 2] * DD + d];
    s3 += (double)X[(size_t)mem[m + 3] * DD + d];
  }
  for (; m < hi; ++m) s0 += (double)X[(size_t)mem[m] * DD + d];
  part[lane][tid & 63] = (s0 + s1) + (s2 + s3);
  __syncthreads();
  if (tid < 64) {
    double tot = (part[0][tid] + part[1][tid]) + (part[2][tid] + part[3][tid]);
    size_t o = (size_t)(r * CC + c) * DD + dchunk * 64 + tid;
    double va = (n > 0) ? tot / (double)n : centOld[o];
    centNew[o] = va;
    centF[o] = (float)va;
  }
}

__global__ __launch_bounds__(256) void norm_kernel(const double* __restrict__ centNew,
                                                   double* __restrict__ cnD,
                                                   float* __restrict__ cnF) {
  __shared__ double red4[4];
  int r = blockIdx.x, c = blockIdx.y, t = threadIdx.x;
  size_t o = (size_t)(r * CC + c) * DD;
  double va = centNew[o + t], vb = centNew[o + t + 256];
  double tot = block_reduce_d(va * va + vb * vb, red4);
  if (t == 0) { cnD[r * CC + c] = tot; cnF[r * CC + c] = (float)tot; }
}

// MFMA sim GEMM: 128x128 tile, 4 waves 2x2, bf16x3 split, K-step 32.
__global__ __launch_bounds__(256) void gemm_kernel(const unsigned short* __restrict__ SH,
                                                   const unsigned short* __restrict__ SL,
                                                   const unsigned short* __restrict__ TH,
                                                   const unsigned short* __restrict__ TL,
                                                   float* __restrict__ sim,
                                                   int rowChunk) {
  __shared__ unsigned short Ah[128 * 40], Al[128 * 40], Bh[128 * 40], Bl[128 * 40];
  int tid = threadIdx.x;
  int wid = tid >> 6, lane = tid & 63, m = lane & 15, q = lane >> 4;
  int waveM = wid >> 1, waveN = wid & 1;
  int rowBase = rowChunk + blockIdx.y * 128;
  int colBase = blockIdx.x * 128;
  f32x4 acc[4][4] = {};
  for (int kc = 0; kc < DD; kc += 32) {
#pragma unroll
    for (int l = 0; l < 2; ++l) {
      int s = l * 256 + tid;
      int row = s >> 2, qq = s & 3;
      int soff = row * 40 + qq * 8;
      size_t ga = (size_t)(rowBase + row) * DD + kc + qq * 8;
      size_t gb = (size_t)(colBase + row) * DD + kc + qq * 8;
      *(uint4*)&Ah[soff] = *(const uint4*)(SH + ga);
      *(uint4*)&Al[soff] = *(const uint4*)(SL + ga);
      *(uint4*)&Bh[soff] = *(const uint4*)(TH + gb);
      *(uint4*)&Bl[soff] = *(const uint4*)(TL + gb);
    }
    __syncthreads();
    short8 ah[4], al[4], bh[4], bl[4];
#pragma unroll
    for (int t = 0; t < 4; ++t) {
      ah[t] = *(short8*)&Ah[(waveM * 64 + t * 16 + m) * 40 + q * 8];
      al[t] = *(short8*)&Al[(waveM * 64 + t * 16 + m) * 40 + q * 8];
      bh[t] = *(short8*)&Bh[(waveN * 64 + t * 16 + m) * 40 + q * 8];
      bl[t] = *(short8*)&Bl[(waveN * 64 + t * 16 + m) * 40 + q * 8];
    }
#pragma unroll
    for (int mt = 0; mt < 4; ++mt)
#pragma unroll
      for (int nt = 0; nt < 4; ++nt) {
        acc[mt][nt] = MFMA_BF16(ah[mt], bh[nt], acc[mt][nt], 0, 0, 0);
        acc[mt][nt] = MFMA_BF16(ah[mt], bl[nt], acc[mt][nt], 0, 0, 0);
        acc[mt][nt] = MFMA_BF16(al[mt], bh[nt], acc[mt][nt], 0, 0, 0);
      }
    __syncthreads();
  }
#pragma unroll
  for (int mt = 0; mt < 4; ++mt)
#pragma unroll
    for (int nt = 0; nt < 4; ++nt) {
      int gcol = colBase + waveN * 64 + nt * 16 + m;
#pragma unroll
      for (int reg = 0; reg < 4; ++reg) {
        int lrow = blockIdx.y * 128 + waveM * 64 + mt * 16 + q * 4 + reg;
        int grow = rowChunk + lrow;
        float v = acc[mt][nt][reg];
        if (grow == gcol) v += 10.0f;
        sim[(size_t)lrow * NN + gcol] = v;
      }
    }
}

// top-16 + margin guard: rows with val16-val17 < FLAGTH get exact resolution.
__global__ __launch_bounds__(256) void topk_kernel(const float* __restrict__ sim,
                                                   int* __restrict__ iknn,
                                                   int rowChunk,
                                                   u64* __restrict__ recs,
                                                   u32* __restrict__ tkcnt) {
  __shared__ float rowv[NN];
  __shared__ u64 red[4];
  int blk = blockIdx.x;
  int tid = threadIdx.x;
  const float* rp = sim + (size_t)blk * NN;
  for (int t = tid; t < NN; t += 256) rowv[t] = rp[t];
  __syncthreads();
  int grow = rowChunk + blk;
  float v16 = 0.f, v17 = 0.f;
  for (int k = 0; k < TOPKK + 1; ++k) {
    u64 best = 0;
    for (int t = tid; t < NN; t += 256) {
      float v = rowv[t];
      u32 u = __float_as_uint(v);
      u = (u & 0x80000000u) ? ~u : (u | 0x80000000u);
      u64 key = ((u64)u << 32) | (u32)(NN - 1 - t);
      best = key > best ? key : best;
    }
    for (int off = 32; off > 0; off >>= 1) {
      u32 lo = (u32)best, hi = (u32)(best >> 32);
      lo = __shfl_down(lo, off, 64); hi = __shfl_down(hi, off, 64);
      u64 o = ((u64)hi << 32) | lo;
      best = o > best ? o : best;
    }
    if ((tid & 63) == 0) red[tid >> 6] = best;
    __syncthreads();
    if (tid == 0) {
      u64 b = red[0];
      for (int w = 1; w < 4; ++w) b = red[w] > b ? red[w] : b;
      u32 ub = (u32)(b >> 32);
      float val = (ub & 0x80000000u) ? __uint_as_float(ub & 0x7FFFFFFFu)
                                     : __uint_as_float(~ub);
      if (k < TOPKK) {
        int t = (NN - 1) - (int)(b & 0xFFFFFFFFu);
        iknn[(size_t)grow * TOPKK + k] = t;
        rowv[t] = -__builtin_inff();
        if (k == TOPKK - 1) v16 = val;
      } else {
        v17 = val;
        if (v16 - v17 < FLAGTH) {
          u32 idx = atomicAdd(tkcnt, 1u);
          if (idx < TKCAP) recs[idx] = ((u64)(u32)grow << 32) | (u64)__float_as_uint(v16);
        }
      }
    }
    __syncthreads();
  }
}

// Exact set-resolution for flagged rows: band candidates re-scored in f64.
__global__ __launch_bounds__(256) void resolve_kernel(const float* __restrict__ sim,
                                                      const float* __restrict__ S,
                                                      const float* __restrict__ T,
                                                      const u64* __restrict__ recs,
                                                      const u32* __restrict__ tkcnt,
                                                      int* __restrict__ iknn,
                                                      int rowChunk) {
  __shared__ int nsure, nband;
  __shared__ int sidx[16];
  __shared__ int bidx[64];
  __shared__ double bval[64];
  int n = (int)*tkcnt; if (n > TKCAP) n = TKCAP;
  int tid = threadIdx.x;
  for (int f = blockIdx.x; f < n; f += gridDim.x) {
    u64 rec = recs[f];
    int grow = (int)(rec >> 32);
    float v16 = __uint_as_float((u32)rec);
    int lrow = grow - rowChunk;
    const float* rp = sim + (size_t)lrow * NN;
    if (tid == 0) { nsure = 0; nband = 0; }
    __syncthreads();
    for (int j = tid; j < NN; j += 256) {
      float v = rp[j];
      if (v > v16 + BAND_TH) {
        int s = atomicAdd(&nsure, 1);
        if (s < 16) sidx[s] = j;
      } else if (v >= v16 - BAND_TH) {
        int s = atomicAdd(&nband, 1);
        if (s < 64) bidx[s] = j;
      }
    }
    __syncthreads();
    int nb = nband > 64 ? 64 : nband;
    if (tid < nb) {
      const float* sp = S + (size_t)grow * DD;
      const float* tp = T + (size_t)bidx[tid] * DD;
      double s = 0.0;
      for (int k = 0; k < DD; ++k) s += (double)sp[k] * (double)tp[k];
      bval[tid] = s;
    }
    __syncthreads();
    if (tid == 0) {
      int w = 0;
      int ns = nsure < 16 ? nsure : 16;
      for (int i2 = 0; i2 < ns; ++i2) iknn[(size_t)grow * TOPKK + w++] = sidx[i2];
      u64 used = 0;
      while (w < TOPKK) {
        int bj = -1; double bv = 0.0;
        for (int i2 = 0; i2 < nb; ++i2) {
          if (used & (1ull << i2)) continue;
          if (bj < 0 || bval[i2] > bv ||
              (bval[i2] == bv && bidx[i2] < bidx[bj])) { bv = bval[i2]; bj = i2; }
        }
        if (bj < 0) break;
        used |= 1ull << bj;
        iknn[(size_t)grow * TOPKK + w++] = bidx[bj];
      }
    }
    __syncthreads();
  }
}

__global__ __launch_bounds__(256) void zero_kernel(float4* __restrict__ out) {
  size_t i = (size_t)blockIdx.x * 256 + threadIdx.x;
  out[i] = make_float4(0.f, 0.f, 0.f, 0.f);
}

__global__ void zeroc_kernel(u32* __restrict__ c) {
  c[threadIdx.x] = 0u;   // 64 counters
}

__global__ __launch_bounds__(256) void scatter_kernel(const float* __restrict__ adj,
                                                      const int* __restrict__ iknn,
                                                      const int* __restrict__ labels,
                                                      float* __restrict__ out) {
  int idx = blockIdx.x * 256 + threadIdx.x;
  int i = idx >> 4;
  int col = iknn[idx];
  int m = 0;
#pragma unroll
  for (int r = 0; r < RR; ++r)
    m |= (labels[(size_t)r * NN + i] == labels[(size_t)r * NN + col]);
  size_t o = (size_t)i * NN + col;
  out[o] = adj[o] + (float)m;
}

extern "C" void kernel_launch(void* const* d_in, const int* in_sizes, int n_in,
                              void* d_out, int out_size, void* d_ws, size_t ws_size,
                              hipStream_t stream) {
  (void)in_sizes; (void)n_in; (void)out_size; (void)ws_size;
  const float* adj     = (const float*)d_in[0];
  const float* student = (const float*)d_in[1];
  const float* teacher = (const float*)d_in[2];
  float* out = (float*)d_out;

  char* p = (char*)d_ws;
  auto alloc = [&](size_t bytes) -> void* {
    void* q = (void*)p; p += (bytes + 255) & ~(size_t)255; return q;
  };
  double* centA  = (double*)alloc((size_t)RR * CC * DD * 8);
  double* centB  = (double*)alloc((size_t)RR * CC * DD * 8);
  float*  centF  = (float*) alloc((size_t)RR * CC * DD * 4);
  double* cnD    = (double*)alloc((size_t)RR * CC * 8);
  float*  cnF    = (float*) alloc((size_t)RR * CC * 4);
  u32*    bits1  = (u32*)   alloc((size_t)RR * NN * 4);
  u32*    bits2  = (u32*)   alloc((size_t)RR * NN * 4);
  u32*    prank  = (u32*)   alloc((size_t)RR * 4 * NN * 4);
  int*    v1     = (int*)   alloc((size_t)RR * NN * 4);
  int*    sel    = (int*)   alloc((size_t)RR * CC * 4);
  int*    labels = (int*)   alloc((size_t)RR * NN * 4);
  int*    bhist  = (int*)   alloc((size_t)RR * 32 * CC * 4);
  int*    boff   = (int*)   alloc((size_t)RR * 32 * CC * 4);
  int*    cstart = (int*)   alloc((size_t)RR * CC * 4);
  int*    cnt    = (int*)   alloc((size_t)RR * CC * 4);
  int*    rib    = (int*)   alloc((size_t)RR * NN * 4);
  int*    member = (int*)   alloc((size_t)RR * NN * 4);
  u32*    flags  = (u32*)   alloc((size_t)(KM_ITERS + 1) * FIXCAP * 4);
  u32*    counters = (u32*) alloc((size_t)64 * 4);
  int*    iknn   = (int*)   alloc((size_t)NN * TOPKK * 4);
  unsigned short* SH = (unsigned short*)alloc((size_t)NN * DD * 2);
  unsigned short* SL = (unsigned short*)alloc((size_t)NN * DD * 2);
  unsigned short* THi = (unsigned short*)alloc((size_t)NN * DD * 2);
  unsigned short* TLo = (unsigned short*)alloc((size_t)NN * DD * 2);
  unsigned short* CHg = (unsigned short*)alloc((size_t)RR * CC * DD * 2);
  unsigned short* CLg = (unsigned short*)alloc((size_t)RR * CC * DD * 2);
  u64*    tkrec  = (u64*)   alloc((size_t)(NN / CHUNK) * TKCAP * 8);
  float*  simc   = (float*) alloc((size_t)CHUNK * NN * 4);

  zeroc_kernel<<<1, 64, 0, stream>>>(counters);

  // --- k-means init: JAX threefry choice(key, 8192, (64,), replace=False) ---
  rng_kernel<<<dim3(RR, 32), 256, 0, stream>>>(bits1, bits2);
  rankpart_kernel<<<dim3(RR, 32, 4), 256, 0, stream>>>(bits1, prank);
  scat1_kernel<<<dim3(RR, 32), 256, 0, stream>>>(prank, v1);
  rankpart_kernel<<<dim3(RR, 32, 4), 256, 0, stream>>>(bits2, prank);
  scat2_kernel<<<dim3(RR, 32), 256, 0, stream>>>(prank, v1, sel);
  init_cent_kernel<<<dim3(RR, CC), 256, 0, stream>>>(teacher, sel, centA, centF, cnD, cnF);

  // --- pre-split inputs to hi/lo bf16 ---
  split_kernel<<<(NN * DD / 8) / 256, 256, 0, stream>>>(student, SH, SL);
  split_kernel<<<(NN * DD / 8) / 256, 256, 0, stream>>>(teacher, THi, TLo);

  // --- 20 Lloyd iterations: MFMA assign + f64 fixup ---
  double* cur = centA; double* nxt = centB;
  for (int it = 0; it < KM_ITERS; ++it) {
    split_kernel<<<(RR * CC * DD / 8) / 256, 256, 0, stream>>>(centF, CHg, CLg);
    assign_kernel<<<dim3(NN / 64, RR), 256, 0, stream>>>(THi, TLo, CHg, CLg, cnF, labels,
                                                         flags + (size_t)it * FIXCAP,
                                                         counters + it);
    fixup_kernel<<<64, 256, 0, stream>>>(teacher, cur, cnD,
                                         flags + (size_t)it * FIXCAP, counters + it, labels);
    hist_kernel<<<dim3(RR, 32), 256, 0, stream>>>(labels, bhist, rib);
    scan_kernel<<<RR, CC, 0, stream>>>(bhist, boff, cstart, cnt);
    fill_kernel<<<dim3(RR, 32), 256, 0, stream>>>(labels, rib, boff, cstart, member);
    update_kernel<<<dim3(RR, CC, 8), 256, 0, stream>>>(teacher, member, cstart, cnt, cur, nxt,
                                                       centF);
    norm_kernel<<<dim3(RR, CC), 256, 0, stream>>>(nxt, cnD, cnF);
    double* t = cur; cur = nxt; nxt = t;
  }
  split_kernel<<<(RR * CC * DD / 8) / 256, 256, 0, stream>>>(centF, CHg, CLg);
  assign_kernel<<<dim3(NN / 64, RR), 256, 0, stream>>>(THi, TLo, CHg, CLg, cnF, labels,
                                                       flags + (size_t)KM_ITERS * FIXCAP,
                                                       counters + KM_ITERS);
  fixup_kernel<<<64, 256, 0, stream>>>(teacher, cur, cnD,
                                       flags + (size_t)KM_ITERS * FIXCAP,
                                       counters + KM_ITERS, labels);

  // --- sim = student @ teacher.T (+10 I), MFMA, chunked; topk + exact resolve ---
  for (int ch = 0; ch < NN / CHUNK; ++ch) {
    gemm_kernel<<<dim3(NN / 128, CHUNK / 128), 256, 0, stream>>>(SH, SL, THi, TLo, simc,
                                                                 ch * CHUNK);
    topk_kernel<<<CHUNK, 256, 0, stream>>>(simc, iknn, ch * CHUNK,
                                           tkrec + (size_t)ch * TKCAP, counters + 32 + ch);
    resolve_kernel<<<128, 256, 0, stream>>>(simc, student, teacher,
                                            tkrec + (size_t)ch * TKCAP, counters + 32 + ch,
                                            iknn, ch * CHUNK);
  }

  // --- pos = 0 everywhere; pos[i, knn] = adj + mask ---
  zero_kernel<<<(unsigned)((size_t)NN * NN / 4 / 256), 256, 0, stream>>>((float4*)out);
  scatter_kernel<<<NN * TOPKK / 256, 256, 0, stream>>>(adj, iknn, labels, out);
}